// Round 1
// baseline (175.485 us; speedup 1.0000x reference)
//
#include <hip/hip_runtime.h>
#include <hip/hip_bf16.h>

#define NB 2
#define NN 30
#define NC 320
#define NM 31
#define HW 4096
#define FMIN_F (-3.40282346638528859812e+38f)

// workspace layout (float offsets)
#define OFF_FSUM   0         // [2*4096]  sum_c nhs
#define OFF_FWRED  8192      // [2*4096]  sum_c nhs*w_reduce
#define OFF_ASUM   16384     // [2*4096]  sum_c attn
#define OFF_AWRED  24576     // [2*4096]  sum_c attn*w_reduce
#define OFF_RSUM   32768     // [2*30*1024] roi-aligned channel-sum
#define OFF_RWRED  94208     // [2*30*1024] roi-aligned w_reduce-dot
#define OFF_FWRAW  155648    // [2*31*4096] raw fw
#define OFF_FGF    409600    // [2*31*4096] fg flag (0/1)
#define OFF_MP     663552    // [64] per-(b,m) max
#define OFF_SCAL   663616    // [64] per-(b,m) sigmoid scale (unpermuted)
#define OFF_WGT    663680    // [2*4096*32] softmax weights, padded stride 32
#define WS_FLOATS  925824
// roi_feats bf16 starts at byte WS_FLOATS*4, size 2*30*1024*320*2 = 39321600 B

__device__ __forceinline__ void get_box(const float* boxes, int b, int n,
                                        float& x1, float& y1, float& bw, float& bh) {
    const float* p = boxes + (b * NN + n) * 4;
    float X1 = p[0] * 64.0f - 0.5f;
    float Y1 = p[1] * 64.0f - 0.5f;
    float X2 = p[2] * 64.0f - 0.5f;
    float Y2 = p[3] * 64.0f - 0.5f;
    x1 = X1; y1 = Y1;
    bw = (X2 - X1) / 32.0f;
    bh = (Y2 - Y1) / 32.0f;
}

// Kernel 1: per-pixel channel reductions of nhs and attn (one wave per pixel)
__global__ void k_reduce(const float* __restrict__ nhs, const float* __restrict__ attn,
                         const float* __restrict__ wred, float* __restrict__ ws) {
    int wave = threadIdx.x >> 6;
    int lane = threadIdx.x & 63;
    int row = blockIdx.x * 4 + wave;   // 0..8191
    const float* nrow = nhs + (size_t)row * NC;
    const float* arow = attn + (size_t)row * NC;
    float s_n = 0.f, w_n = 0.f, s_a = 0.f, w_a = 0.f;
#pragma unroll
    for (int k = 0; k < 5; k++) {
        int c = lane + 64 * k;
        float wr = wred[c];
        float vn = nrow[c];
        float va = arow[c];
        s_n += vn; w_n += vn * wr;
        s_a += va; w_a += va * wr;
    }
#pragma unroll
    for (int off = 32; off > 0; off >>= 1) {
        s_n += __shfl_down(s_n, off, 64);
        w_n += __shfl_down(w_n, off, 64);
        s_a += __shfl_down(s_a, off, 64);
        w_a += __shfl_down(w_a, off, 64);
    }
    if (lane == 0) {
        ws[OFF_FSUM + row]  = s_n;
        ws[OFF_FWRED + row] = w_n;
        ws[OFF_ASUM + row]  = s_a;
        ws[OFF_AWRED + row] = w_a;
    }
}

// Kernel 2: ROI-align (64x64 samples avg 2x2 -> 32x32) of the channel-reduced maps
__global__ void k_roi_sums(const float* __restrict__ boxes, float* __restrict__ ws) {
    int idx = blockIdx.x * blockDim.x + threadIdx.x;  // B*N*1024
    if (idx >= NB * NN * 1024) return;
    int q = idx & 31;
    int p = (idx >> 5) & 31;
    int bn = idx >> 10;
    int n = bn % NN;
    int b = bn / NN;
    float x1, y1, bw, bh;
    get_box(boxes, b, n, x1, y1, bw, bh);
    const float* fsum  = ws + OFF_FSUM + b * HW;
    const float* fwred = ws + OFF_FWRED + b * HW;
    float accs = 0.f, accw = 0.f;
#pragma unroll
    for (int di = 0; di < 2; di++) {
#pragma unroll
        for (int dj = 0; dj < 2; dj++) {
            float y = y1 + ((float)p + 0.25f + 0.5f * (float)di) * bh;
            float x = x1 + ((float)q + 0.25f + 0.5f * (float)dj) * bw;
            bool valid = (y > -1.0f) && (y < 64.0f) && (x > -1.0f) && (x < 64.0f);
            if (valid) {
                float yc = fminf(fmaxf(y, 0.0f), 63.0f);
                float xc = fminf(fmaxf(x, 0.0f), 63.0f);
                int iy0 = (int)floorf(yc), ix0 = (int)floorf(xc);
                int iy1 = min(iy0 + 1, 63), ix1 = min(ix0 + 1, 63);
                float wy = yc - (float)iy0, wx = xc - (float)ix0;
                float w00 = (1.f - wy) * (1.f - wx), w01 = (1.f - wy) * wx;
                float w10 = wy * (1.f - wx), w11 = wy * wx;
                accs += w00 * fsum[iy0 * 64 + ix0] + w01 * fsum[iy0 * 64 + ix1]
                      + w10 * fsum[iy1 * 64 + ix0] + w11 * fsum[iy1 * 64 + ix1];
                accw += w00 * fwred[iy0 * 64 + ix0] + w01 * fwred[iy0 * 64 + ix1]
                      + w10 * fwred[iy1 * 64 + ix0] + w11 * fwred[iy1 * 64 + ix1];
            }
        }
    }
    ws[OFF_RSUM + idx]  = accs * 0.25f;
    ws[OFF_RWRED + idx] = accw * 0.25f;
}

// Kernel 3: fw / fg per (b,m,pixel) + per-(b,m) max-pool
__global__ void k_fw(const float* __restrict__ boxes, const int* __restrict__ masks,
                     float* __restrict__ ws) {
    int bm = blockIdx.x;          // 0..61
    int b = bm / NM, m = bm % NM;
    __shared__ float red[256];
    float locmax = -INFINITY;
    if (m == 0) {
        for (int pix = threadIdx.x; pix < HW; pix += 256) {
            float fwv = ws[OFF_AWRED + b * HW + pix];
            float fgv = (ws[OFF_ASUM + b * HW + pix] != 0.0f) ? 1.0f : 0.0f;
            ws[OFF_FWRAW + (size_t)bm * HW + pix] = fwv;
            ws[OFF_FGF + (size_t)bm * HW + pix] = fgv;
            locmax = fmaxf(locmax, fwv);
        }
    } else {
        int n = m - 1;
        float x1, y1, bw, bh;
        get_box(boxes, b, n, x1, y1, bw, bh);
        int msk = masks[b * NN + n];
        const float* rs = ws + OFF_RSUM + (b * NN + n) * 1024;
        const float* rw = ws + OFF_RWRED + (b * NN + n) * 1024;
        for (int pix = threadIdx.x; pix < HW; pix += 256) {
            int h = pix >> 6, wp = pix & 63;
            float fwv = 0.0f, fgv = 0.0f;
            if (msk) {
                float ry = ((float)h - y1) / bh - 0.5f;
                float rx = ((float)wp - x1) / bw - 0.5f;
                bool valid = (ry > -1.0f) && (ry < 32.0f) && (rx > -1.0f) && (rx < 32.0f);
                if (valid) {
                    float yc = fminf(fmaxf(ry, 0.0f), 31.0f);
                    float xc = fminf(fmaxf(rx, 0.0f), 31.0f);
                    int iy0 = (int)floorf(yc), ix0 = (int)floorf(xc);
                    int iy1 = min(iy0 + 1, 31), ix1 = min(ix0 + 1, 31);
                    float wy = yc - (float)iy0, wx = xc - (float)ix0;
                    float w00 = (1.f - wy) * (1.f - wx), w01 = (1.f - wy) * wx;
                    float w10 = wy * (1.f - wx), w11 = wy * wx;
                    fwv = w00 * rw[iy0 * 32 + ix0] + w01 * rw[iy0 * 32 + ix1]
                        + w10 * rw[iy1 * 32 + ix0] + w11 * rw[iy1 * 32 + ix1];
                    float su = w00 * rs[iy0 * 32 + ix0] + w01 * rs[iy0 * 32 + ix1]
                             + w10 * rs[iy1 * 32 + ix0] + w11 * rs[iy1 * 32 + ix1];
                    fgv = (su != 0.0f) ? 1.0f : 0.0f;
                }
            }
            ws[OFF_FWRAW + (size_t)bm * HW + pix] = fwv;
            ws[OFF_FGF + (size_t)bm * HW + pix] = fgv;
            locmax = fmaxf(locmax, fwv);
        }
    }
    red[threadIdx.x] = locmax;
    __syncthreads();
    for (int s = 128; s > 0; s >>= 1) {
        if (threadIdx.x < s) red[threadIdx.x] = fmaxf(red[threadIdx.x], red[threadIdx.x + s]);
        __syncthreads();
    }
    if (threadIdx.x == 0) ws[OFF_MP + bm] = red[0];
}

// Kernel 4: permute -> MLP -> sigmoid -> un-permute scatter (tiny)
__global__ void k_mlp(const int* __restrict__ perm, const float* __restrict__ w1,
                      const float* __restrict__ b1, const float* __restrict__ w2,
                      const float* __restrict__ b2, float* __restrict__ ws) {
    __shared__ float mpg[NB][NM];
    __shared__ float hbuf[NB][NM];
    int tid = threadIdx.x;     // 64 threads
    int b = tid >> 5, j = tid & 31;
    bool act = (j < NM);
    if (act) {
        float v;
        if (j == 0) v = ws[OFF_MP + b * NM];
        else        v = ws[OFF_MP + b * NM + 1 + perm[j - 1]];
        mpg[b][j] = v;
    }
    __syncthreads();
    if (act) {
        float a = b1[j];
        for (int k = 0; k < NM; k++) a += mpg[b][k] * w1[k * NM + j];
        hbuf[b][j] = fmaxf(a, 0.0f);
    }
    __syncthreads();
    if (act) {
        float a = b2[j];
        for (int k = 0; k < NM; k++) a += hbuf[b][k] * w2[k * NM + j];
        float sig = 1.0f / (1.0f + expf(-a));
        if (j == 0) ws[OFF_SCAL + b * NM] = sig;
        else        ws[OFF_SCAL + b * NM + 1 + perm[j - 1]] = sig;
    }
}

// Kernel 5: per-pixel 31-way softmax -> weights
__global__ void k_soft(float* __restrict__ ws) {
    int idx = blockIdx.x * 256 + threadIdx.x;   // B*HW
    if (idx >= NB * HW) return;
    int b = idx / HW, pix = idx % HW;
    float z[NM];
    float mx = -INFINITY;
#pragma unroll
    for (int m = 0; m < NM; m++) {
        float fwv = ws[OFF_FWRAW + ((size_t)(b * NM + m)) * HW + pix];
        float fgv = ws[OFF_FGF + ((size_t)(b * NM + m)) * HW + pix];
        float s = ws[OFF_SCAL + b * NM + m];
        float zz = (fgv != 0.0f) ? fwv * s : FMIN_F;
        z[m] = zz;
        mx = fmaxf(mx, zz);
    }
    float sum = 0.0f;
#pragma unroll
    for (int m = 0; m < NM; m++) {
        float e = expf(z[m] - mx);
        z[m] = e;
        sum += e;
    }
    float inv = 1.0f / sum;
#pragma unroll
    for (int m = 0; m < NM; m++)
        ws[OFF_WGT + (size_t)idx * 32 + m] = z[m] * inv;
}

// Kernel 6: full-channel roi_feats (bf16), only for mask!=0 instances.
// block = one roi cell (b,n,p,q); thread = channel (320 threads)
__global__ void k_roifeat(const float* __restrict__ nhs, const float* __restrict__ boxes,
                          const int* __restrict__ masks, __hip_bfloat16* __restrict__ roif) {
    int cell = blockIdx.x;       // B*N*1024
    int q = cell & 31;
    int p = (cell >> 5) & 31;
    int bn = cell >> 10;
    int n = bn % NN;
    int b = bn / NN;
    if (masks[b * NN + n] == 0) return;
    float x1, y1, bw, bh;
    get_box(boxes, b, n, x1, y1, bw, bh);
    float wc[4][4];
    int ic[4][4];
    bool vv[4];
#pragma unroll
    for (int s_ = 0; s_ < 4; s_++) {
        int di = s_ >> 1, dj = s_ & 1;
        float y = y1 + ((float)p + 0.25f + 0.5f * (float)di) * bh;
        float x = x1 + ((float)q + 0.25f + 0.5f * (float)dj) * bw;
        vv[s_] = (y > -1.0f) && (y < 64.0f) && (x > -1.0f) && (x < 64.0f);
        float yc = fminf(fmaxf(y, 0.0f), 63.0f);
        float xc = fminf(fmaxf(x, 0.0f), 63.0f);
        int iy0 = (int)floorf(yc), ix0 = (int)floorf(xc);
        int iy1 = min(iy0 + 1, 63), ix1 = min(ix0 + 1, 63);
        float wy = yc - (float)iy0, wx = xc - (float)ix0;
        wc[s_][0] = (1.f - wy) * (1.f - wx);
        wc[s_][1] = (1.f - wy) * wx;
        wc[s_][2] = wy * (1.f - wx);
        wc[s_][3] = wy * wx;
        ic[s_][0] = iy0 * 64 + ix0;
        ic[s_][1] = iy0 * 64 + ix1;
        ic[s_][2] = iy1 * 64 + ix0;
        ic[s_][3] = iy1 * 64 + ix1;
    }
    int c = threadIdx.x;
    const float* fb = nhs + ((size_t)b * HW) * NC;
    float acc = 0.0f;
#pragma unroll
    for (int s_ = 0; s_ < 4; s_++) {
        if (vv[s_]) {
            acc += wc[s_][0] * fb[(size_t)ic[s_][0] * NC + c]
                 + wc[s_][1] * fb[(size_t)ic[s_][1] * NC + c]
                 + wc[s_][2] * fb[(size_t)ic[s_][2] * NC + c]
                 + wc[s_][3] * fb[(size_t)ic[s_][3] * NC + c];
        }
    }
    roif[(size_t)cell * NC + c] = __float2bfloat16(acc * 0.25f);
}

// Kernel 7: final gather: out = w0*attn + sum_n wn * bilinear(roi_feats)
// block = one pixel; thread = channel (320)
__global__ void k_final(const float* __restrict__ attn, const float* __restrict__ boxes,
                        const float* __restrict__ ws, const __hip_bfloat16* __restrict__ roif,
                        float* __restrict__ out) {
    int idx = blockIdx.x;        // B*HW
    int b = idx / HW, pix = idx % HW;
    int h = pix >> 6, wp = pix & 63;
    const float* wrow = ws + OFF_WGT + (size_t)idx * 32;
    int tid = threadIdx.x;       // channel
    float w0 = wrow[0];
    float acc = 0.0f;
    for (int n = 0; n < NN; n++) {
        float wn = wrow[n + 1];
        if (wn == 0.0f) continue;   // uniform across block
        float x1, y1, bw, bh;
        get_box(boxes, b, n, x1, y1, bw, bh);
        float ry = ((float)h - y1) / bh - 0.5f;
        float rx = ((float)wp - x1) / bw - 0.5f;
        float yc = fminf(fmaxf(ry, 0.0f), 31.0f);
        float xc = fminf(fmaxf(rx, 0.0f), 31.0f);
        int iy0 = (int)floorf(yc), ix0 = (int)floorf(xc);
        int iy1 = min(iy0 + 1, 31), ix1 = min(ix0 + 1, 31);
        float wy = yc - (float)iy0, wx = xc - (float)ix0;
        float w00 = (1.f - wy) * (1.f - wx) * wn, w01 = (1.f - wy) * wx * wn;
        float w10 = wy * (1.f - wx) * wn, w11 = wy * wx * wn;
        size_t base = (size_t)(b * NN + n) * 1024;
        const __hip_bfloat16* r00 = roif + (base + iy0 * 32 + ix0) * NC;
        const __hip_bfloat16* r01 = roif + (base + iy0 * 32 + ix1) * NC;
        const __hip_bfloat16* r10 = roif + (base + iy1 * 32 + ix0) * NC;
        const __hip_bfloat16* r11 = roif + (base + iy1 * 32 + ix1) * NC;
        acc += w00 * __bfloat162float(r00[tid]) + w01 * __bfloat162float(r01[tid])
             + w10 * __bfloat162float(r10[tid]) + w11 * __bfloat162float(r11[tid]);
    }
    const float* arow = attn + (size_t)idx * NC;
    out[(size_t)idx * NC + tid] = arow[tid] * w0 + acc;
}

extern "C" void kernel_launch(void* const* d_in, const int* in_sizes, int n_in,
                              void* d_out, int out_size, void* d_ws, size_t ws_size,
                              hipStream_t stream) {
    const float* nhs   = (const float*)d_in[0];
    const float* attn  = (const float*)d_in[1];
    const float* boxes = (const float*)d_in[2];
    const int*   masks = (const int*)d_in[3];
    const int*   perm  = (const int*)d_in[4];
    const float* wred  = (const float*)d_in[5];
    const float* w1    = (const float*)d_in[6];
    const float* b1    = (const float*)d_in[7];
    const float* w2    = (const float*)d_in[8];
    const float* b2    = (const float*)d_in[9];
    float* out = (float*)d_out;
    float* ws = (float*)d_ws;
    __hip_bfloat16* roif = (__hip_bfloat16*)((char*)d_ws + (size_t)WS_FLOATS * 4);

    k_reduce<<<2048, 256, 0, stream>>>(nhs, attn, wred, ws);
    k_roi_sums<<<240, 256, 0, stream>>>(boxes, ws);
    k_fw<<<NB * NM, 256, 0, stream>>>(boxes, masks, ws);
    k_mlp<<<1, 64, 0, stream>>>(perm, w1, b1, w2, b2, ws);
    k_soft<<<32, 256, 0, stream>>>(ws);
    k_roifeat<<<NB * NN * 1024, 320, 0, stream>>>(nhs, boxes, masks, roif);
    k_final<<<NB * HW, 320, 0, stream>>>(attn, boxes, ws, roif, out);
}

// Round 2
// 159.088 us; speedup vs baseline: 1.1031x; 1.1031x over previous
//
#include <hip/hip_runtime.h>
#include <hip/hip_bf16.h>

#define NB 2
#define NN 30
#define NC 320
#define NM 31
#define HW 4096
#define FMIN_F (-3.40282346638528859812e+38f)

// workspace layout (float offsets)
#define OFF_FSUM   0         // [2*4096]  sum_c nhs
#define OFF_FWRED  8192      // [2*4096]  sum_c nhs*w_reduce
#define OFF_ASUM   16384     // [2*4096]  sum_c attn
#define OFF_AWRED  24576     // [2*4096]  sum_c attn*w_reduce
#define OFF_RSUM   32768     // [2*30*1024] roi-aligned channel-sum
#define OFF_RWRED  94208     // [2*30*1024] roi-aligned w_reduce-dot
#define OFF_Z      155648    // [2*31*4096] fw with -FLT_MAX sentinel where fg=false
#define OFF_MP     409600    // [64] per-(b,m) max of raw fw
#define OFF_WGT    409664    // [32*8192] softmax weights, layout [m][b*HW+pix]
#define WS_FLOATS  671808
// roi_feats bf16 at byte WS_FLOATS*4 (=2687232, 16B aligned), 2*30*1024*320*2 B

__device__ __forceinline__ void get_box(const float* boxes, int b, int n,
                                        float& x1, float& y1, float& bw, float& bh) {
    const float* p = boxes + (b * NN + n) * 4;
    float X1 = p[0] * 64.0f - 0.5f;
    float Y1 = p[1] * 64.0f - 0.5f;
    float X2 = p[2] * 64.0f - 0.5f;
    float Y2 = p[3] * 64.0f - 0.5f;
    x1 = X1; y1 = Y1;
    bw = (X2 - X1) / 32.0f;
    bh = (Y2 - Y1) / 32.0f;
}

__device__ __forceinline__ unsigned short f2bf(float f) {
    __hip_bfloat16 h = __float2bfloat16(f);
    return *reinterpret_cast<unsigned short*>(&h);
}
__device__ __forceinline__ float bf2f(unsigned short u) {
    return __uint_as_float(((unsigned int)u) << 16);
}

// Kernel 1: per-pixel channel reductions of nhs and attn (one wave per row, float4)
__global__ void k_reduce(const float* __restrict__ nhs, const float* __restrict__ attn,
                         const float* __restrict__ wred, float* __restrict__ ws) {
    int wave = threadIdx.x >> 6;
    int lane = threadIdx.x & 63;
    int row = blockIdx.x * 4 + wave;   // 0..8191
    const float4* n4 = (const float4*)(nhs + (size_t)row * NC);
    const float4* a4 = (const float4*)(attn + (size_t)row * NC);
    const float4* w4 = (const float4*)wred;
    float4 wv = w4[lane];
    float4 nv = n4[lane];
    float4 av = a4[lane];
    float s_n = nv.x + nv.y + nv.z + nv.w;
    float w_n = nv.x * wv.x + nv.y * wv.y + nv.z * wv.z + nv.w * wv.w;
    float s_a = av.x + av.y + av.z + av.w;
    float w_a = av.x * wv.x + av.y * wv.y + av.z * wv.z + av.w * wv.w;
    if (lane < 16) {   // second chunk: float4 index 64..79
        float4 wv2 = w4[lane + 64];
        float4 nv2 = n4[lane + 64];
        float4 av2 = a4[lane + 64];
        s_n += nv2.x + nv2.y + nv2.z + nv2.w;
        w_n += nv2.x * wv2.x + nv2.y * wv2.y + nv2.z * wv2.z + nv2.w * wv2.w;
        s_a += av2.x + av2.y + av2.z + av2.w;
        w_a += av2.x * wv2.x + av2.y * wv2.y + av2.z * wv2.z + av2.w * wv2.w;
    }
#pragma unroll
    for (int off = 32; off > 0; off >>= 1) {
        s_n += __shfl_down(s_n, off, 64);
        w_n += __shfl_down(w_n, off, 64);
        s_a += __shfl_down(s_a, off, 64);
        w_a += __shfl_down(w_a, off, 64);
    }
    if (lane == 0) {
        ws[OFF_FSUM + row]  = s_n;
        ws[OFF_FWRED + row] = w_n;
        ws[OFF_ASUM + row]  = s_a;
        ws[OFF_AWRED + row] = w_a;
    }
}

// Kernel 2: ROI-align (2x2 sample avg -> 32x32) of the channel-reduced maps
__global__ void k_roi_sums(const float* __restrict__ boxes, float* __restrict__ ws) {
    int idx = blockIdx.x * blockDim.x + threadIdx.x;  // B*N*1024
    if (idx >= NB * NN * 1024) return;
    int q = idx & 31;
    int p = (idx >> 5) & 31;
    int bn = idx >> 10;
    int n = bn % NN;
    int b = bn / NN;
    float x1, y1, bw, bh;
    get_box(boxes, b, n, x1, y1, bw, bh);
    const float* fsum  = ws + OFF_FSUM + b * HW;
    const float* fwred = ws + OFF_FWRED + b * HW;
    float accs = 0.f, accw = 0.f;
#pragma unroll
    for (int di = 0; di < 2; di++) {
#pragma unroll
        for (int dj = 0; dj < 2; dj++) {
            float y = y1 + ((float)p + 0.25f + 0.5f * (float)di) * bh;
            float x = x1 + ((float)q + 0.25f + 0.5f * (float)dj) * bw;
            bool valid = (y > -1.0f) && (y < 64.0f) && (x > -1.0f) && (x < 64.0f);
            if (valid) {
                float yc = fminf(fmaxf(y, 0.0f), 63.0f);
                float xc = fminf(fmaxf(x, 0.0f), 63.0f);
                int iy0 = (int)floorf(yc), ix0 = (int)floorf(xc);
                int iy1 = min(iy0 + 1, 63), ix1 = min(ix0 + 1, 63);
                float wy = yc - (float)iy0, wx = xc - (float)ix0;
                float w00 = (1.f - wy) * (1.f - wx), w01 = (1.f - wy) * wx;
                float w10 = wy * (1.f - wx), w11 = wy * wx;
                accs += w00 * fsum[iy0 * 64 + ix0] + w01 * fsum[iy0 * 64 + ix1]
                      + w10 * fsum[iy1 * 64 + ix0] + w11 * fsum[iy1 * 64 + ix1];
                accw += w00 * fwred[iy0 * 64 + ix0] + w01 * fwred[iy0 * 64 + ix1]
                      + w10 * fwred[iy1 * 64 + ix0] + w11 * fwred[iy1 * 64 + ix1];
            }
        }
    }
    ws[OFF_RSUM + idx]  = accs * 0.25f;
    ws[OFF_RWRED + idx] = accw * 0.25f;
}

// Kernel 3: z (fw gated w/ sentinel) per (b,m,pixel) + per-(b,m) max of raw fw
__global__ void k_fw(const float* __restrict__ boxes, const int* __restrict__ masks,
                     float* __restrict__ ws) {
    int bm = blockIdx.x;          // 0..61
    int b = bm / NM, m = bm % NM;
    __shared__ float red[256];
    float locmax = -INFINITY;
    if (m == 0) {
        for (int pix = threadIdx.x; pix < HW; pix += 256) {
            float fwv = ws[OFF_AWRED + b * HW + pix];
            bool fg = (ws[OFF_ASUM + b * HW + pix] != 0.0f);
            ws[OFF_Z + (size_t)bm * HW + pix] = fg ? fwv : FMIN_F;
            locmax = fmaxf(locmax, fwv);
        }
    } else {
        int n = m - 1;
        float x1, y1, bw, bh;
        get_box(boxes, b, n, x1, y1, bw, bh);
        int msk = masks[b * NN + n];
        const float* rs = ws + OFF_RSUM + (b * NN + n) * 1024;
        const float* rw = ws + OFF_RWRED + (b * NN + n) * 1024;
        for (int pix = threadIdx.x; pix < HW; pix += 256) {
            int h = pix >> 6, wp = pix & 63;
            float fwv = 0.0f;
            bool fg = false;
            if (msk) {
                float ry = ((float)h - y1) / bh - 0.5f;
                float rx = ((float)wp - x1) / bw - 0.5f;
                bool valid = (ry > -1.0f) && (ry < 32.0f) && (rx > -1.0f) && (rx < 32.0f);
                if (valid) {
                    float yc = fminf(fmaxf(ry, 0.0f), 31.0f);
                    float xc = fminf(fmaxf(rx, 0.0f), 31.0f);
                    int iy0 = (int)floorf(yc), ix0 = (int)floorf(xc);
                    int iy1 = min(iy0 + 1, 31), ix1 = min(ix0 + 1, 31);
                    float wy = yc - (float)iy0, wx = xc - (float)ix0;
                    float w00 = (1.f - wy) * (1.f - wx), w01 = (1.f - wy) * wx;
                    float w10 = wy * (1.f - wx), w11 = wy * wx;
                    fwv = w00 * rw[iy0 * 32 + ix0] + w01 * rw[iy0 * 32 + ix1]
                        + w10 * rw[iy1 * 32 + ix0] + w11 * rw[iy1 * 32 + ix1];
                    float su = w00 * rs[iy0 * 32 + ix0] + w01 * rs[iy0 * 32 + ix1]
                             + w10 * rs[iy1 * 32 + ix0] + w11 * rs[iy1 * 32 + ix1];
                    fg = (su != 0.0f);
                }
            }
            ws[OFF_Z + (size_t)bm * HW + pix] = fg ? fwv : FMIN_F;
            locmax = fmaxf(locmax, fwv);
        }
    }
    red[threadIdx.x] = locmax;
    __syncthreads();
    for (int s = 128; s > 0; s >>= 1) {
        if (threadIdx.x < s) red[threadIdx.x] = fmaxf(red[threadIdx.x], red[threadIdx.x + s]);
        __syncthreads();
    }
    if (threadIdx.x == 0) ws[OFF_MP + bm] = red[0];
}

// Kernel 4: fused MLP (redundant per block, in LDS) + per-pixel 31-way softmax
__global__ void k_soft(const int* __restrict__ perm, const float* __restrict__ w1,
                       const float* __restrict__ b1, const float* __restrict__ w2,
                       const float* __restrict__ b2, float* __restrict__ ws) {
    __shared__ float mpg[NB][NM], hb[NB][NM], scal[NB][NM];
    int t = threadIdx.x;
    if (t < NB * NM) {
        int b = t / NM, j = t % NM;
        float v = (j == 0) ? ws[OFF_MP + b * NM]
                           : ws[OFF_MP + b * NM + 1 + perm[j - 1]];
        mpg[b][j] = v;
    }
    __syncthreads();
    if (t < NB * NM) {
        int b = t / NM, j = t % NM;
        float a = b1[j];
        for (int k = 0; k < NM; k++) a += mpg[b][k] * w1[k * NM + j];
        hb[b][j] = fmaxf(a, 0.0f);
    }
    __syncthreads();
    if (t < NB * NM) {
        int b = t / NM, j = t % NM;
        float a = b2[j];
        for (int k = 0; k < NM; k++) a += hb[b][k] * w2[k * NM + j];
        float sig = 1.0f / (1.0f + expf(-a));
        if (j == 0) scal[b][0] = sig;
        else        scal[b][1 + perm[j - 1]] = sig;
    }
    __syncthreads();

    int idx = blockIdx.x * 256 + t;    // B*HW
    int b = idx >> 12, pix = idx & 4095;
    float z[NM];
    float mx = -INFINITY;
#pragma unroll
    for (int m = 0; m < NM; m++) {
        float v = ws[OFF_Z + ((size_t)(b * NM + m)) * HW + pix];
        float zz = (v == FMIN_F) ? FMIN_F : v * scal[b][m];
        z[m] = zz;
        mx = fmaxf(mx, zz);
    }
    float sum = 0.0f;
#pragma unroll
    for (int m = 0; m < NM; m++) {
        float e = expf(z[m] - mx);
        z[m] = e;
        sum += e;
    }
    float inv = 1.0f / sum;
#pragma unroll
    for (int m = 0; m < NM; m++)
        ws[OFF_WGT + m * (NB * HW) + idx] = z[m] * inv;   // [m][idx] coalesced
}

// Kernel 5: full-channel roi_feats (bf16) for masked-in instances.
// block = 4 cells x 80 lanes; thread = 4 channels (float4 in, ushort4 out)
__global__ void k_roifeat(const float* __restrict__ nhs, const float* __restrict__ boxes,
                          const int* __restrict__ masks, unsigned short* __restrict__ roif) {
    int bn = blockIdx.x >> 8;          // 4 cells per block, 256 blocks per (b,n)
    int n = bn % NN;
    int b = bn / NN;
    if (masks[b * NN + n] == 0) return;
    int tid = threadIdx.x;
    int cid = tid / 80;
    int v = tid - cid * 80;
    int cell = blockIdx.x * 4 + cid;
    int q = cell & 31;
    int p = (cell >> 5) & 31;
    float x1, y1, bw, bh;
    get_box(boxes, b, n, x1, y1, bw, bh);
    float wc[4][4];
    int ic[4][4];
    bool vv[4];
#pragma unroll
    for (int s_ = 0; s_ < 4; s_++) {
        int di = s_ >> 1, dj = s_ & 1;
        float y = y1 + ((float)p + 0.25f + 0.5f * (float)di) * bh;
        float x = x1 + ((float)q + 0.25f + 0.5f * (float)dj) * bw;
        vv[s_] = (y > -1.0f) && (y < 64.0f) && (x > -1.0f) && (x < 64.0f);
        float yc = fminf(fmaxf(y, 0.0f), 63.0f);
        float xc = fminf(fmaxf(x, 0.0f), 63.0f);
        int iy0 = (int)floorf(yc), ix0 = (int)floorf(xc);
        int iy1 = min(iy0 + 1, 63), ix1 = min(ix0 + 1, 63);
        float wy = yc - (float)iy0, wx = xc - (float)ix0;
        wc[s_][0] = (1.f - wy) * (1.f - wx);
        wc[s_][1] = (1.f - wy) * wx;
        wc[s_][2] = wy * (1.f - wx);
        wc[s_][3] = wy * wx;
        ic[s_][0] = iy0 * 64 + ix0;
        ic[s_][1] = iy0 * 64 + ix1;
        ic[s_][2] = iy1 * 64 + ix0;
        ic[s_][3] = iy1 * 64 + ix1;
    }
    const float4* fb4 = (const float4*)(nhs + (size_t)b * HW * NC);
    float4 acc = make_float4(0.f, 0.f, 0.f, 0.f);
#pragma unroll
    for (int s_ = 0; s_ < 4; s_++) {
        if (vv[s_]) {
#pragma unroll
            for (int t_ = 0; t_ < 4; t_++) {
                float w = wc[s_][t_];
                float4 fv = fb4[ic[s_][t_] * 80 + v];
                acc.x += w * fv.x; acc.y += w * fv.y;
                acc.z += w * fv.z; acc.w += w * fv.w;
            }
        }
    }
    ushort4 pk;
    pk.x = f2bf(acc.x * 0.25f);
    pk.y = f2bf(acc.y * 0.25f);
    pk.z = f2bf(acc.z * 0.25f);
    pk.w = f2bf(acc.w * 0.25f);
    ((ushort4*)roif)[(size_t)cell * 80 + v] = pk;
}

// Kernel 6: final gather: out = w0*attn + sum_n wn * bilinear(roi_feats)
// block = 4 pixels x 80 lanes; thread = 4 channels
__global__ void k_final(const float* __restrict__ attn, const float* __restrict__ boxes,
                        const float* __restrict__ ws, const unsigned short* __restrict__ roif,
                        float* __restrict__ out) {
    int tid = threadIdx.x;
    int pid = tid / 80;
    int v = tid - pid * 80;
    int idx = blockIdx.x * 4 + pid;    // B*HW
    int b = idx >> 12, pix = idx & 4095;
    int h = pix >> 6, wp = pix & 63;
    float w0 = ws[OFF_WGT + idx];
    float4 a4 = ((const float4*)attn)[(size_t)idx * 80 + v];
    float4 acc;
    acc.x = a4.x * w0; acc.y = a4.y * w0; acc.z = a4.z * w0; acc.w = a4.w * w0;
    const ushort4* r4 = (const ushort4*)roif;
    for (int n = 0; n < NN; n++) {
        float wn = ws[OFF_WGT + (n + 1) * (NB * HW) + idx];
        if (wn == 0.0f) continue;
        float x1, y1, bw, bh;
        get_box(boxes, b, n, x1, y1, bw, bh);
        float ry = ((float)h - y1) / bh - 0.5f;
        float rx = ((float)wp - x1) / bw - 0.5f;
        float yc = fminf(fmaxf(ry, 0.0f), 31.0f);
        float xc = fminf(fmaxf(rx, 0.0f), 31.0f);
        int iy0 = (int)floorf(yc), ix0 = (int)floorf(xc);
        int iy1 = min(iy0 + 1, 31), ix1 = min(ix0 + 1, 31);
        float wy = yc - (float)iy0, wx = xc - (float)ix0;
        float w00 = (1.f - wy) * (1.f - wx) * wn, w01 = (1.f - wy) * wx * wn;
        float w10 = wy * (1.f - wx) * wn, w11 = wy * wx * wn;
        size_t base = ((size_t)(b * NN + n)) << 10;
        ushort4 u00 = r4[(base + iy0 * 32 + ix0) * 80 + v];
        ushort4 u01 = r4[(base + iy0 * 32 + ix1) * 80 + v];
        ushort4 u10 = r4[(base + iy1 * 32 + ix0) * 80 + v];
        ushort4 u11 = r4[(base + iy1 * 32 + ix1) * 80 + v];
        acc.x += w00 * bf2f(u00.x) + w01 * bf2f(u01.x) + w10 * bf2f(u10.x) + w11 * bf2f(u11.x);
        acc.y += w00 * bf2f(u00.y) + w01 * bf2f(u01.y) + w10 * bf2f(u10.y) + w11 * bf2f(u11.y);
        acc.z += w00 * bf2f(u00.z) + w01 * bf2f(u01.z) + w10 * bf2f(u10.z) + w11 * bf2f(u11.z);
        acc.w += w00 * bf2f(u00.w) + w01 * bf2f(u01.w) + w10 * bf2f(u10.w) + w11 * bf2f(u11.w);
    }
    ((float4*)out)[(size_t)idx * 80 + v] = acc;
}

extern "C" void kernel_launch(void* const* d_in, const int* in_sizes, int n_in,
                              void* d_out, int out_size, void* d_ws, size_t ws_size,
                              hipStream_t stream) {
    const float* nhs   = (const float*)d_in[0];
    const float* attn  = (const float*)d_in[1];
    const float* boxes = (const float*)d_in[2];
    const int*   masks = (const int*)d_in[3];
    const int*   perm  = (const int*)d_in[4];
    const float* wred  = (const float*)d_in[5];
    const float* w1    = (const float*)d_in[6];
    const float* b1    = (const float*)d_in[7];
    const float* w2    = (const float*)d_in[8];
    const float* b2    = (const float*)d_in[9];
    float* out = (float*)d_out;
    float* ws = (float*)d_ws;
    unsigned short* roif = (unsigned short*)((char*)d_ws + (size_t)WS_FLOATS * 4);

    k_reduce<<<2048, 256, 0, stream>>>(nhs, attn, wred, ws);
    k_roi_sums<<<240, 256, 0, stream>>>(boxes, ws);
    k_fw<<<NB * NM, 256, 0, stream>>>(boxes, masks, ws);
    k_soft<<<32, 256, 0, stream>>>(perm, w1, b1, w2, b2, ws);
    k_roifeat<<<NB * NN * 256, 320, 0, stream>>>(nhs, boxes, masks, roif);
    k_final<<<NB * HW / 4, 320, 0, stream>>>(attn, boxes, ws, roif, out);
}

// Round 4
// 142.374 us; speedup vs baseline: 1.2326x; 1.1174x over previous
//
#include <hip/hip_runtime.h>
#include <hip/hip_bf16.h>

#define NB 2
#define NN 30
#define NC 320
#define NM 31
#define HW 4096
#define FMIN_F (-3.40282346638528859812e+38f)

typedef float nfloat4 __attribute__((ext_vector_type(4)));

// workspace layout (float offsets)
#define OFF_FSUM   0         // [2*4096]  sum_c nhs
#define OFF_FWRED  8192      // [2*4096]  sum_c nhs*w_reduce
#define OFF_ASUM   16384     // [2*4096]  sum_c attn
#define OFF_AWRED  24576     // [2*4096]  sum_c attn*w_reduce
#define OFF_Z      32768     // [62*4096] fw with -FLT_MAX sentinel where fg=false
#define OFF_MP     286720    // [64] per-(b,m) max of raw fw
#define OFF_AMSK   286784    // [8192] uint32 active-ROI bitmask per pixel
#define OFF_WGT    294976    // [31*8192] softmax weights, layout [m][b*HW+pix]
#define WS_FLOATS  548928
// roi_feats bf16 at byte WS_FLOATS*4 (=2195712, 16B aligned), 2*30*1024*320*2 B

__device__ __forceinline__ void get_box(const float* boxes, int b, int n,
                                        float& x1, float& y1, float& bw, float& bh) {
    const float* p = boxes + (b * NN + n) * 4;
    float X1 = p[0] * 64.0f - 0.5f;
    float Y1 = p[1] * 64.0f - 0.5f;
    float X2 = p[2] * 64.0f - 0.5f;
    float Y2 = p[3] * 64.0f - 0.5f;
    x1 = X1; y1 = Y1;
    bw = (X2 - X1) / 32.0f;
    bh = (Y2 - Y1) / 32.0f;
}

__device__ __forceinline__ unsigned short f2bf(float f) {
    __hip_bfloat16 h = __float2bfloat16(f);
    return *reinterpret_cast<unsigned short*>(&h);
}
__device__ __forceinline__ float bf2f(unsigned short u) {
    return __uint_as_float(((unsigned int)u) << 16);
}

// Kernel 1: per-pixel channel reductions of nhs and attn (one wave per row, float4)
__global__ void k_reduce(const float* __restrict__ nhs, const float* __restrict__ attn,
                         const float* __restrict__ wred, float* __restrict__ ws) {
    int wave = threadIdx.x >> 6;
    int lane = threadIdx.x & 63;
    int row = blockIdx.x * 4 + wave;   // 0..8191
    const float4* n4 = (const float4*)(nhs + (size_t)row * NC);
    const float4* a4 = (const float4*)(attn + (size_t)row * NC);
    const float4* w4 = (const float4*)wred;
    float4 wv = w4[lane];
    float4 nv = n4[lane];
    float4 av = a4[lane];
    float s_n = nv.x + nv.y + nv.z + nv.w;
    float w_n = nv.x * wv.x + nv.y * wv.y + nv.z * wv.z + nv.w * wv.w;
    float s_a = av.x + av.y + av.z + av.w;
    float w_a = av.x * wv.x + av.y * wv.y + av.z * wv.z + av.w * wv.w;
    if (lane < 16) {   // second chunk: float4 index 64..79
        float4 wv2 = w4[lane + 64];
        float4 nv2 = n4[lane + 64];
        float4 av2 = a4[lane + 64];
        s_n += nv2.x + nv2.y + nv2.z + nv2.w;
        w_n += nv2.x * wv2.x + nv2.y * wv2.y + nv2.z * wv2.z + nv2.w * wv2.w;
        s_a += av2.x + av2.y + av2.z + av2.w;
        w_a += av2.x * wv2.x + av2.y * wv2.y + av2.z * wv2.z + av2.w * wv2.w;
    }
#pragma unroll
    for (int off = 32; off > 0; off >>= 1) {
        s_n += __shfl_down(s_n, off, 64);
        w_n += __shfl_down(w_n, off, 64);
        s_a += __shfl_down(s_a, off, 64);
        w_a += __shfl_down(w_a, off, 64);
    }
    if (lane == 0) {
        ws[OFF_FSUM + row]  = s_n;
        ws[OFF_FWRED + row] = w_n;
        ws[OFF_ASUM + row]  = s_a;
        ws[OFF_AWRED + row] = w_a;
    }
}

// Kernel 2 (fused roi_sums + fw): per (b,m) block, ROI-align the channel-reduced
// maps into LDS (m>=1), then unpool to all 4096 pixels -> Z (+sentinel) + max.
__global__ void k_fw(const float* __restrict__ boxes, const int* __restrict__ masks,
                     float* __restrict__ ws) {
    int bm = blockIdx.x;          // 0..61
    int b = bm / NM, m = bm % NM;
    __shared__ float rs[1024], rw[1024];
    __shared__ float red[256];
    float locmax = -INFINITY;
    int tid = threadIdx.x;
    if (m == 0) {
        for (int pix = tid; pix < HW; pix += 256) {
            float fwv = ws[OFF_AWRED + b * HW + pix];
            bool fg = (ws[OFF_ASUM + b * HW + pix] != 0.0f);
            ws[OFF_Z + (size_t)bm * HW + pix] = fg ? fwv : FMIN_F;
            locmax = fmaxf(locmax, fwv);
        }
    } else {
        int n = m - 1;
        int msk = masks[b * NN + n];
        if (msk) {
            float x1, y1, bw, bh;
            get_box(boxes, b, n, x1, y1, bw, bh);
            const float* fsum  = ws + OFF_FSUM + b * HW;
            const float* fwred = ws + OFF_FWRED + b * HW;
            for (int cell = tid; cell < 1024; cell += 256) {
                int q = cell & 31, p = cell >> 5;
                float accs = 0.f, accw = 0.f;
#pragma unroll
                for (int di = 0; di < 2; di++) {
#pragma unroll
                    for (int dj = 0; dj < 2; dj++) {
                        float y = y1 + ((float)p + 0.25f + 0.5f * (float)di) * bh;
                        float x = x1 + ((float)q + 0.25f + 0.5f * (float)dj) * bw;
                        bool valid = (y > -1.0f) && (y < 64.0f) && (x > -1.0f) && (x < 64.0f);
                        if (valid) {
                            float yc = fminf(fmaxf(y, 0.0f), 63.0f);
                            float xc = fminf(fmaxf(x, 0.0f), 63.0f);
                            int iy0 = (int)floorf(yc), ix0 = (int)floorf(xc);
                            int iy1 = min(iy0 + 1, 63), ix1 = min(ix0 + 1, 63);
                            float wy = yc - (float)iy0, wx = xc - (float)ix0;
                            float w00 = (1.f - wy) * (1.f - wx), w01 = (1.f - wy) * wx;
                            float w10 = wy * (1.f - wx), w11 = wy * wx;
                            accs += w00 * fsum[iy0 * 64 + ix0] + w01 * fsum[iy0 * 64 + ix1]
                                  + w10 * fsum[iy1 * 64 + ix0] + w11 * fsum[iy1 * 64 + ix1];
                            accw += w00 * fwred[iy0 * 64 + ix0] + w01 * fwred[iy0 * 64 + ix1]
                                  + w10 * fwred[iy1 * 64 + ix0] + w11 * fwred[iy1 * 64 + ix1];
                        }
                    }
                }
                rs[cell] = accs * 0.25f;
                rw[cell] = accw * 0.25f;
            }
            __syncthreads();
            for (int pix = tid; pix < HW; pix += 256) {
                int h = pix >> 6, wp = pix & 63;
                float fwv = 0.0f;
                bool fg = false;
                float ry = ((float)h - y1) / bh - 0.5f;
                float rx = ((float)wp - x1) / bw - 0.5f;
                bool valid = (ry > -1.0f) && (ry < 32.0f) && (rx > -1.0f) && (rx < 32.0f);
                if (valid) {
                    float yc = fminf(fmaxf(ry, 0.0f), 31.0f);
                    float xc = fminf(fmaxf(rx, 0.0f), 31.0f);
                    int iy0 = (int)floorf(yc), ix0 = (int)floorf(xc);
                    int iy1 = min(iy0 + 1, 31), ix1 = min(ix0 + 1, 31);
                    float wy = yc - (float)iy0, wx = xc - (float)ix0;
                    float w00 = (1.f - wy) * (1.f - wx), w01 = (1.f - wy) * wx;
                    float w10 = wy * (1.f - wx), w11 = wy * wx;
                    fwv = w00 * rw[iy0 * 32 + ix0] + w01 * rw[iy0 * 32 + ix1]
                        + w10 * rw[iy1 * 32 + ix0] + w11 * rw[iy1 * 32 + ix1];
                    float su = w00 * rs[iy0 * 32 + ix0] + w01 * rs[iy0 * 32 + ix1]
                             + w10 * rs[iy1 * 32 + ix0] + w11 * rs[iy1 * 32 + ix1];
                    fg = (su != 0.0f);
                }
                ws[OFF_Z + (size_t)bm * HW + pix] = fg ? fwv : FMIN_F;
                locmax = fmaxf(locmax, fwv);
            }
        } else {
            // masked-out: fw == 0 everywhere, fg false
            for (int pix = tid; pix < HW; pix += 256)
                ws[OFF_Z + (size_t)bm * HW + pix] = FMIN_F;
            locmax = 0.0f;
        }
    }
    red[tid] = locmax;
    __syncthreads();
    for (int s = 128; s > 0; s >>= 1) {
        if (tid < s) red[tid] = fmaxf(red[tid], red[tid + s]);
        __syncthreads();
    }
    if (tid == 0) ws[OFF_MP + bm] = red[0];
}

// Kernel 3: fused MLP (redundant per block, in LDS) + per-pixel 31-way softmax
// + per-pixel active-ROI bitmask
__global__ void k_soft(const int* __restrict__ perm, const float* __restrict__ w1,
                       const float* __restrict__ b1, const float* __restrict__ w2,
                       const float* __restrict__ b2, float* __restrict__ ws) {
    __shared__ float mpg[NB][NM], hb[NB][NM], scal[NB][NM];
    int t = threadIdx.x;
    if (t < NB * NM) {
        int b = t / NM, j = t % NM;
        float v = (j == 0) ? ws[OFF_MP + b * NM]
                           : ws[OFF_MP + b * NM + 1 + perm[j - 1]];
        mpg[b][j] = v;
    }
    __syncthreads();
    if (t < NB * NM) {
        int b = t / NM, j = t % NM;
        float a = b1[j];
        for (int k = 0; k < NM; k++) a += mpg[b][k] * w1[k * NM + j];
        hb[b][j] = fmaxf(a, 0.0f);
    }
    __syncthreads();
    if (t < NB * NM) {
        int b = t / NM, j = t % NM;
        float a = b2[j];
        for (int k = 0; k < NM; k++) a += hb[b][k] * w2[k * NM + j];
        float sig = 1.0f / (1.0f + expf(-a));
        if (j == 0) scal[b][0] = sig;
        else        scal[b][1 + perm[j - 1]] = sig;
    }
    __syncthreads();

    int idx = blockIdx.x * 256 + t;    // B*HW
    int b = idx >> 12, pix = idx & 4095;
    float z[NM];
    float mx = -INFINITY;
#pragma unroll
    for (int m = 0; m < NM; m++) {
        float v = ws[OFF_Z + ((size_t)(b * NM + m)) * HW + pix];
        float zz = (v == FMIN_F) ? FMIN_F : v * scal[b][m];
        z[m] = zz;
        mx = fmaxf(mx, zz);
    }
    float sum = 0.0f;
#pragma unroll
    for (int m = 0; m < NM; m++) {
        float e = expf(z[m] - mx);
        z[m] = e;
        sum += e;
    }
    float inv = 1.0f / sum;
    unsigned amask = 0u;
#pragma unroll
    for (int m = 0; m < NM; m++) {
        float w = z[m] * inv;
        ws[OFF_WGT + m * (NB * HW) + idx] = w;   // [m][idx] coalesced
        if (m >= 1 && w != 0.0f) amask |= (1u << (m - 1));
    }
    ((unsigned*)(ws + OFF_AMSK))[idx] = amask;
}

// Kernel 4: full-channel roi_feats (bf16) for masked-in instances.
// block = 4 cells x 80 lanes; thread = 4 channels (float4 in, ushort4 out)
__global__ void k_roifeat(const float* __restrict__ nhs, const float* __restrict__ boxes,
                          const int* __restrict__ masks, unsigned short* __restrict__ roif) {
    int bn = blockIdx.x >> 8;          // 4 cells per block, 256 blocks per (b,n)
    int n = bn % NN;
    int b = bn / NN;
    if (masks[b * NN + n] == 0) return;
    int tid = threadIdx.x;
    int cid = tid / 80;
    int v = tid - cid * 80;
    int cell = blockIdx.x * 4 + cid;
    int q = cell & 31;
    int p = (cell >> 5) & 31;
    float x1, y1, bw, bh;
    get_box(boxes, b, n, x1, y1, bw, bh);
    float wc[4][4];
    int ic[4][4];
    bool vv[4];
#pragma unroll
    for (int s_ = 0; s_ < 4; s_++) {
        int di = s_ >> 1, dj = s_ & 1;
        float y = y1 + ((float)p + 0.25f + 0.5f * (float)di) * bh;
        float x = x1 + ((float)q + 0.25f + 0.5f * (float)dj) * bw;
        vv[s_] = (y > -1.0f) && (y < 64.0f) && (x > -1.0f) && (x < 64.0f);
        float yc = fminf(fmaxf(y, 0.0f), 63.0f);
        float xc = fminf(fmaxf(x, 0.0f), 63.0f);
        int iy0 = (int)floorf(yc), ix0 = (int)floorf(xc);
        int iy1 = min(iy0 + 1, 63), ix1 = min(ix0 + 1, 63);
        float wy = yc - (float)iy0, wx = xc - (float)ix0;
        wc[s_][0] = (1.f - wy) * (1.f - wx);
        wc[s_][1] = (1.f - wy) * wx;
        wc[s_][2] = wy * (1.f - wx);
        wc[s_][3] = wy * wx;
        ic[s_][0] = iy0 * 64 + ix0;
        ic[s_][1] = iy0 * 64 + ix1;
        ic[s_][2] = iy1 * 64 + ix0;
        ic[s_][3] = iy1 * 64 + ix1;
    }
    const float4* fb4 = (const float4*)(nhs + (size_t)b * HW * NC);
    float4 acc = make_float4(0.f, 0.f, 0.f, 0.f);
#pragma unroll
    for (int s_ = 0; s_ < 4; s_++) {
        if (vv[s_]) {
#pragma unroll
            for (int t_ = 0; t_ < 4; t_++) {
                float w = wc[s_][t_];
                float4 fv = fb4[ic[s_][t_] * 80 + v];
                acc.x += w * fv.x; acc.y += w * fv.y;
                acc.z += w * fv.z; acc.w += w * fv.w;
            }
        }
    }
    ushort4 pk;
    pk.x = f2bf(acc.x * 0.25f);
    pk.y = f2bf(acc.y * 0.25f);
    pk.z = f2bf(acc.z * 0.25f);
    pk.w = f2bf(acc.w * 0.25f);
    ((ushort4*)roif)[(size_t)cell * 80 + v] = pk;
}

// Kernel 5: final gather: out = w0*attn + sum_{active n} wn * bilinear(roi_feats)
// block = 4 pixels x 80 lanes; thread = 4 channels
__global__ void k_final(const float* __restrict__ attn, const float* __restrict__ boxes,
                        const float* __restrict__ ws, const unsigned short* __restrict__ roif,
                        float* __restrict__ out) {
    int tid = threadIdx.x;
    int pid = tid / 80;
    int v = tid - pid * 80;
    int idx = blockIdx.x * 4 + pid;    // B*HW
    int b = idx >> 12, pix = idx & 4095;
    int h = pix >> 6, wp = pix & 63;
    float w0 = ws[OFF_WGT + idx];
    unsigned amask = ((const unsigned*)(ws + OFF_AMSK))[idx];
    float4 a4 = ((const float4*)attn)[(size_t)idx * 80 + v];
    float4 acc;
    acc.x = a4.x * w0; acc.y = a4.y * w0; acc.z = a4.z * w0; acc.w = a4.w * w0;
    const ushort4* r4 = (const ushort4*)roif;
    while (amask) {
        int n = __ffs(amask) - 1;
        amask &= amask - 1;
        float wn = ws[OFF_WGT + (n + 1) * (NB * HW) + idx];
        float x1, y1, bw, bh;
        get_box(boxes, b, n, x1, y1, bw, bh);
        float ry = ((float)h - y1) / bh - 0.5f;
        float rx = ((float)wp - x1) / bw - 0.5f;
        float yc = fminf(fmaxf(ry, 0.0f), 31.0f);
        float xc = fminf(fmaxf(rx, 0.0f), 31.0f);
        int iy0 = (int)floorf(yc), ix0 = (int)floorf(xc);
        int iy1 = min(iy0 + 1, 31), ix1 = min(ix0 + 1, 31);
        float wy = yc - (float)iy0, wx = xc - (float)ix0;
        float w00 = (1.f - wy) * (1.f - wx) * wn, w01 = (1.f - wy) * wx * wn;
        float w10 = wy * (1.f - wx) * wn, w11 = wy * wx * wn;
        size_t base = ((size_t)(b * NN + n)) << 10;
        ushort4 u00 = r4[(base + iy0 * 32 + ix0) * 80 + v];
        ushort4 u01 = r4[(base + iy0 * 32 + ix1) * 80 + v];
        ushort4 u10 = r4[(base + iy1 * 32 + ix0) * 80 + v];
        ushort4 u11 = r4[(base + iy1 * 32 + ix1) * 80 + v];
        acc.x += w00 * bf2f(u00.x) + w01 * bf2f(u01.x) + w10 * bf2f(u10.x) + w11 * bf2f(u11.x);
        acc.y += w00 * bf2f(u00.y) + w01 * bf2f(u01.y) + w10 * bf2f(u10.y) + w11 * bf2f(u11.y);
        acc.z += w00 * bf2f(u00.z) + w01 * bf2f(u01.z) + w10 * bf2f(u10.z) + w11 * bf2f(u11.z);
        acc.w += w00 * bf2f(u00.w) + w01 * bf2f(u01.w) + w10 * bf2f(u10.w) + w11 * bf2f(u11.w);
    }
    nfloat4 nv = { acc.x, acc.y, acc.z, acc.w };
    __builtin_nontemporal_store(nv, ((nfloat4*)out) + (size_t)idx * 80 + v);
}

extern "C" void kernel_launch(void* const* d_in, const int* in_sizes, int n_in,
                              void* d_out, int out_size, void* d_ws, size_t ws_size,
                              hipStream_t stream) {
    const float* nhs   = (const float*)d_in[0];
    const float* attn  = (const float*)d_in[1];
    const float* boxes = (const float*)d_in[2];
    const int*   masks = (const int*)d_in[3];
    const int*   perm  = (const int*)d_in[4];
    const float* wred  = (const float*)d_in[5];
    const float* w1    = (const float*)d_in[6];
    const float* b1    = (const float*)d_in[7];
    const float* w2    = (const float*)d_in[8];
    const float* b2    = (const float*)d_in[9];
    float* out = (float*)d_out;
    float* ws = (float*)d_ws;
    unsigned short* roif = (unsigned short*)((char*)d_ws + (size_t)WS_FLOATS * 4);

    k_roifeat<<<NB * NN * 256, 320, 0, stream>>>(nhs, boxes, masks, roif);
    k_reduce<<<2048, 256, 0, stream>>>(nhs, attn, wred, ws);
    k_fw<<<NB * NM, 256, 0, stream>>>(boxes, masks, ws);
    k_soft<<<32, 256, 0, stream>>>(perm, w1, b1, w2, b2, ws);
    k_final<<<NB * HW / 4, 320, 0, stream>>>(attn, boxes, ws, roif, out);
}

// Round 5
// 131.580 us; speedup vs baseline: 1.3337x; 1.0820x over previous
//
#include <hip/hip_runtime.h>
#include <hip/hip_bf16.h>

#define NB 2
#define NN 30
#define NC 320
#define NM 31
#define HW 4096
#define FMIN_F (-3.40282346638528859812e+38f)

typedef float nfloat4 __attribute__((ext_vector_type(4)));

// workspace layout (float offsets)
#define OFF_FSUM   0         // [2*4096]  sum_c nhs
#define OFF_FWRED  8192      // [2*4096]  sum_c nhs*w_reduce
#define OFF_ASUM   16384     // [2*4096]  sum_c attn
#define OFF_AWRED  24576     // [2*4096]  sum_c attn*w_reduce
#define OFF_Z      32768     // [62*4096] fw with -FLT_MAX sentinel where fg=false
#define OFF_MP     286720    // [64] per-(b,m) max of raw fw
#define WS_FLOATS  286784
// roi_feats bf16 at byte WS_FLOATS*4 (=1147136, 16B aligned), 2*30*1024*320*2 B

#define GRID_ROIF (NB * NN * 256)      // 15360
#define GRID_RED  1639                 // ceil(8192/5)

__device__ __forceinline__ void get_box(const float* boxes, int b, int n,
                                        float& x1, float& y1, float& bw, float& bh) {
    const float* p = boxes + (b * NN + n) * 4;
    float X1 = p[0] * 64.0f - 0.5f;
    float Y1 = p[1] * 64.0f - 0.5f;
    float X2 = p[2] * 64.0f - 0.5f;
    float Y2 = p[3] * 64.0f - 0.5f;
    x1 = X1; y1 = Y1;
    bw = (X2 - X1) / 32.0f;
    bh = (Y2 - Y1) / 32.0f;
}

__device__ __forceinline__ unsigned short f2bf(float f) {
    __hip_bfloat16 h = __float2bfloat16(f);
    return *reinterpret_cast<unsigned short*>(&h);
}
__device__ __forceinline__ float bf2f(unsigned short u) {
    return __uint_as_float(((unsigned int)u) << 16);
}

// ---- part A: full-channel roi_feats (bf16) for masked-in instances ----
// block = 4 cells x 80 lanes; thread = 4 channels (float4 in, ushort4 out)
__device__ void do_roifeat(int blk, const float* __restrict__ nhs,
                           const float* __restrict__ boxes,
                           const int* __restrict__ masks,
                           unsigned short* __restrict__ roif) {
    int bn = blk >> 8;                 // 4 cells per block, 256 blocks per (b,n)
    int n = bn % NN;
    int b = bn / NN;
    if (masks[b * NN + n] == 0) return;
    int tid = threadIdx.x;
    int cid = tid / 80;
    int v = tid - cid * 80;
    int cell = blk * 4 + cid;
    int q = cell & 31;
    int p = (cell >> 5) & 31;
    float x1, y1, bw, bh;
    get_box(boxes, b, n, x1, y1, bw, bh);
    float wc[4][4];
    int ic[4][4];
    bool vv[4];
#pragma unroll
    for (int s_ = 0; s_ < 4; s_++) {
        int di = s_ >> 1, dj = s_ & 1;
        float y = y1 + ((float)p + 0.25f + 0.5f * (float)di) * bh;
        float x = x1 + ((float)q + 0.25f + 0.5f * (float)dj) * bw;
        vv[s_] = (y > -1.0f) && (y < 64.0f) && (x > -1.0f) && (x < 64.0f);
        float yc = fminf(fmaxf(y, 0.0f), 63.0f);
        float xc = fminf(fmaxf(x, 0.0f), 63.0f);
        int iy0 = (int)floorf(yc), ix0 = (int)floorf(xc);
        int iy1 = min(iy0 + 1, 63), ix1 = min(ix0 + 1, 63);
        float wy = yc - (float)iy0, wx = xc - (float)ix0;
        wc[s_][0] = (1.f - wy) * (1.f - wx);
        wc[s_][1] = (1.f - wy) * wx;
        wc[s_][2] = wy * (1.f - wx);
        wc[s_][3] = wy * wx;
        ic[s_][0] = iy0 * 64 + ix0;
        ic[s_][1] = iy0 * 64 + ix1;
        ic[s_][2] = iy1 * 64 + ix0;
        ic[s_][3] = iy1 * 64 + ix1;
    }
    const float4* fb4 = (const float4*)(nhs + (size_t)b * HW * NC);
    float4 acc = make_float4(0.f, 0.f, 0.f, 0.f);
#pragma unroll
    for (int s_ = 0; s_ < 4; s_++) {
        if (vv[s_]) {
#pragma unroll
            for (int t_ = 0; t_ < 4; t_++) {
                float w = wc[s_][t_];
                float4 fv = fb4[ic[s_][t_] * 80 + v];
                acc.x += w * fv.x; acc.y += w * fv.y;
                acc.z += w * fv.z; acc.w += w * fv.w;
            }
        }
    }
    ushort4 pk;
    pk.x = f2bf(acc.x * 0.25f);
    pk.y = f2bf(acc.y * 0.25f);
    pk.z = f2bf(acc.z * 0.25f);
    pk.w = f2bf(acc.w * 0.25f);
    ((ushort4*)roif)[(size_t)cell * 80 + v] = pk;
}

// ---- part B: per-pixel channel reductions (one wave per row, float4) ----
__device__ void do_reduce(int rblk, const float* __restrict__ nhs,
                          const float* __restrict__ attn,
                          const float* __restrict__ wred, float* __restrict__ ws) {
    int wave = threadIdx.x >> 6;       // 0..4 (320 threads)
    int lane = threadIdx.x & 63;
    int row = rblk * 5 + wave;
    if (row >= NB * HW) return;
    const float4* n4 = (const float4*)(nhs + (size_t)row * NC);
    const float4* a4 = (const float4*)(attn + (size_t)row * NC);
    const float4* w4 = (const float4*)wred;
    float4 wv = w4[lane];
    float4 nv = n4[lane];
    float4 av = a4[lane];
    float s_n = nv.x + nv.y + nv.z + nv.w;
    float w_n = nv.x * wv.x + nv.y * wv.y + nv.z * wv.z + nv.w * wv.w;
    float s_a = av.x + av.y + av.z + av.w;
    float w_a = av.x * wv.x + av.y * wv.y + av.z * wv.z + av.w * wv.w;
    if (lane < 16) {                   // second chunk: float4 index 64..79
        float4 wv2 = w4[lane + 64];
        float4 nv2 = n4[lane + 64];
        float4 av2 = a4[lane + 64];
        s_n += nv2.x + nv2.y + nv2.z + nv2.w;
        w_n += nv2.x * wv2.x + nv2.y * wv2.y + nv2.z * wv2.z + nv2.w * wv2.w;
        s_a += av2.x + av2.y + av2.z + av2.w;
        w_a += av2.x * wv2.x + av2.y * wv2.y + av2.z * wv2.z + av2.w * wv2.w;
    }
#pragma unroll
    for (int off = 32; off > 0; off >>= 1) {
        s_n += __shfl_down(s_n, off, 64);
        w_n += __shfl_down(w_n, off, 64);
        s_a += __shfl_down(s_a, off, 64);
        w_a += __shfl_down(w_a, off, 64);
    }
    if (lane == 0) {
        ws[OFF_FSUM + row]  = s_n;
        ws[OFF_FWRED + row] = w_n;
        ws[OFF_ASUM + row]  = s_a;
        ws[OFF_AWRED + row] = w_a;
    }
}

// Kernel 1: roifeat (blocks [0,15360)) || reduce (blocks [15360,15360+1639))
__global__ void k_stage1(const float* __restrict__ nhs, const float* __restrict__ attn,
                         const float* __restrict__ boxes, const int* __restrict__ masks,
                         const float* __restrict__ wred, float* __restrict__ ws,
                         unsigned short* __restrict__ roif) {
    int blk = blockIdx.x;
    if (blk < GRID_ROIF) {
        do_roifeat(blk, nhs, boxes, masks, roif);
    } else {
        do_reduce(blk - GRID_ROIF, nhs, attn, wred, ws);
    }
}

// Kernel 2 (fused roi_sums + fw): per (b,m) block, ROI-align the channel-reduced
// maps into LDS (m>=1), then unpool to all 4096 pixels -> Z (+sentinel) + max.
__global__ void k_fw(const float* __restrict__ boxes, const int* __restrict__ masks,
                     float* __restrict__ ws) {
    int bm = blockIdx.x;          // 0..61
    int b = bm / NM, m = bm % NM;
    __shared__ float rs[1024], rw[1024];
    __shared__ float red[256];
    float locmax = -INFINITY;
    int tid = threadIdx.x;
    if (m == 0) {
        for (int pix = tid; pix < HW; pix += 256) {
            float fwv = ws[OFF_AWRED + b * HW + pix];
            bool fg = (ws[OFF_ASUM + b * HW + pix] != 0.0f);
            ws[OFF_Z + (size_t)bm * HW + pix] = fg ? fwv : FMIN_F;
            locmax = fmaxf(locmax, fwv);
        }
    } else {
        int n = m - 1;
        int msk = masks[b * NN + n];
        if (msk) {
            float x1, y1, bw, bh;
            get_box(boxes, b, n, x1, y1, bw, bh);
            const float* fsum  = ws + OFF_FSUM + b * HW;
            const float* fwred = ws + OFF_FWRED + b * HW;
            for (int cell = tid; cell < 1024; cell += 256) {
                int q = cell & 31, p = cell >> 5;
                float accs = 0.f, accw = 0.f;
#pragma unroll
                for (int di = 0; di < 2; di++) {
#pragma unroll
                    for (int dj = 0; dj < 2; dj++) {
                        float y = y1 + ((float)p + 0.25f + 0.5f * (float)di) * bh;
                        float x = x1 + ((float)q + 0.25f + 0.5f * (float)dj) * bw;
                        bool valid = (y > -1.0f) && (y < 64.0f) && (x > -1.0f) && (x < 64.0f);
                        if (valid) {
                            float yc = fminf(fmaxf(y, 0.0f), 63.0f);
                            float xc = fminf(fmaxf(x, 0.0f), 63.0f);
                            int iy0 = (int)floorf(yc), ix0 = (int)floorf(xc);
                            int iy1 = min(iy0 + 1, 63), ix1 = min(ix0 + 1, 63);
                            float wy = yc - (float)iy0, wx = xc - (float)ix0;
                            float w00 = (1.f - wy) * (1.f - wx), w01 = (1.f - wy) * wx;
                            float w10 = wy * (1.f - wx), w11 = wy * wx;
                            accs += w00 * fsum[iy0 * 64 + ix0] + w01 * fsum[iy0 * 64 + ix1]
                                  + w10 * fsum[iy1 * 64 + ix0] + w11 * fsum[iy1 * 64 + ix1];
                            accw += w00 * fwred[iy0 * 64 + ix0] + w01 * fwred[iy0 * 64 + ix1]
                                  + w10 * fwred[iy1 * 64 + ix0] + w11 * fwred[iy1 * 64 + ix1];
                        }
                    }
                }
                rs[cell] = accs * 0.25f;
                rw[cell] = accw * 0.25f;
            }
            __syncthreads();
            for (int pix = tid; pix < HW; pix += 256) {
                int h = pix >> 6, wp = pix & 63;
                float fwv = 0.0f;
                bool fg = false;
                float ry = ((float)h - y1) / bh - 0.5f;
                float rx = ((float)wp - x1) / bw - 0.5f;
                bool valid = (ry > -1.0f) && (ry < 32.0f) && (rx > -1.0f) && (rx < 32.0f);
                if (valid) {
                    float yc = fminf(fmaxf(ry, 0.0f), 31.0f);
                    float xc = fminf(fmaxf(rx, 0.0f), 31.0f);
                    int iy0 = (int)floorf(yc), ix0 = (int)floorf(xc);
                    int iy1 = min(iy0 + 1, 31), ix1 = min(ix0 + 1, 31);
                    float wy = yc - (float)iy0, wx = xc - (float)ix0;
                    float w00 = (1.f - wy) * (1.f - wx), w01 = (1.f - wy) * wx;
                    float w10 = wy * (1.f - wx), w11 = wy * wx;
                    fwv = w00 * rw[iy0 * 32 + ix0] + w01 * rw[iy0 * 32 + ix1]
                        + w10 * rw[iy1 * 32 + ix0] + w11 * rw[iy1 * 32 + ix1];
                    float su = w00 * rs[iy0 * 32 + ix0] + w01 * rs[iy0 * 32 + ix1]
                             + w10 * rs[iy1 * 32 + ix0] + w11 * rs[iy1 * 32 + ix1];
                    fg = (su != 0.0f);
                }
                ws[OFF_Z + (size_t)bm * HW + pix] = fg ? fwv : FMIN_F;
                locmax = fmaxf(locmax, fwv);
            }
        } else {
            // masked-out: fw == 0 everywhere, fg false
            for (int pix = tid; pix < HW; pix += 256)
                ws[OFF_Z + (size_t)bm * HW + pix] = FMIN_F;
            locmax = 0.0f;
        }
    }
    red[tid] = locmax;
    __syncthreads();
    for (int s = 128; s > 0; s >>= 1) {
        if (tid < s) red[tid] = fmaxf(red[tid], red[tid + s]);
        __syncthreads();
    }
    if (tid == 0) ws[OFF_MP + bm] = red[0];
}

// Kernel 3: fused MLP + per-pixel softmax + final gather.
// block = 4 pixels x 80 lanes; thread = 4 channels.
__global__ void k_final(const float* __restrict__ attn, const float* __restrict__ boxes,
                        const int* __restrict__ perm, const float* __restrict__ w1,
                        const float* __restrict__ b1, const float* __restrict__ w2,
                        const float* __restrict__ b2, const float* __restrict__ ws,
                        const unsigned short* __restrict__ roif, float* __restrict__ out) {
    __shared__ float mpg[NM], hb[NM], scal[32], wbuf[4][32];
    int t = threadIdx.x;
    int idx0 = blockIdx.x * 4;         // all 4 pixels share the same b
    int b = idx0 >> 12;

    // stage 1: tiny MLP (redundant per block)
    if (t < NM) {
        mpg[t] = (t == 0) ? ws[OFF_MP + b * NM]
                          : ws[OFF_MP + b * NM + 1 + perm[t - 1]];
    }
    __syncthreads();
    if (t < NM) {
        float a = b1[t];
#pragma unroll
        for (int k = 0; k < NM; k++) a += mpg[k] * w1[k * NM + t];
        hb[t] = fmaxf(a, 0.0f);
    }
    __syncthreads();
    if (t < NM) {
        float a = b2[t];
#pragma unroll
        for (int k = 0; k < NM; k++) a += hb[k] * w2[k * NM + t];
        float sig = 1.0f / (1.0f + expf(-a));
        if (t == 0) scal[0] = sig;
        else        scal[1 + perm[t - 1]] = sig;
    }
    __syncthreads();

    // stage 2: softmax for the 4 pixels (threads 0..127; 32 lanes per pixel)
    if (t < 128) {
        int pg = t >> 5, m = t & 31;
        int pix = (idx0 + pg) & 4095;
        float zz = FMIN_F;
        if (m < NM) {
            float v = ws[OFF_Z + (size_t)(b * NM + m) * HW + pix];
            zz = (v == FMIN_F) ? FMIN_F : v * scal[m];
        }
        float mx = zz;
#pragma unroll
        for (int off = 16; off > 0; off >>= 1)
            mx = fmaxf(mx, __shfl_xor(mx, off, 64));
        float e = (m < NM) ? expf(zz - mx) : 0.0f;
        float s = e;
#pragma unroll
        for (int off = 16; off > 0; off >>= 1)
            s += __shfl_xor(s, off, 64);
        if (m < NM) wbuf[pg][m] = e / s;
    }
    __syncthreads();

    // stage 3: gather
    int pid = t / 80;
    int v = t - pid * 80;
    int idx = idx0 + pid;
    int pix = idx & 4095;
    int h = pix >> 6, wp = pix & 63;
    float w0 = wbuf[pid][0];
    float4 a4 = ((const float4*)attn)[(size_t)idx * 80 + v];
    float4 acc;
    acc.x = a4.x * w0; acc.y = a4.y * w0; acc.z = a4.z * w0; acc.w = a4.w * w0;
    const ushort4* r4 = (const ushort4*)roif;
    for (int n = 0; n < NN; n++) {
        float wn = wbuf[pid][n + 1];
        if (wn == 0.0f) continue;      // uniform across the 80-lane group
        float x1, y1, bw, bh;
        get_box(boxes, b, n, x1, y1, bw, bh);
        float ry = ((float)h - y1) / bh - 0.5f;
        float rx = ((float)wp - x1) / bw - 0.5f;
        float yc = fminf(fmaxf(ry, 0.0f), 31.0f);
        float xc = fminf(fmaxf(rx, 0.0f), 31.0f);
        int iy0 = (int)floorf(yc), ix0 = (int)floorf(xc);
        int iy1 = min(iy0 + 1, 31), ix1 = min(ix0 + 1, 31);
        float wy = yc - (float)iy0, wx = xc - (float)ix0;
        float w00 = (1.f - wy) * (1.f - wx) * wn, w01 = (1.f - wy) * wx * wn;
        float w10 = wy * (1.f - wx) * wn, w11 = wy * wx * wn;
        size_t base = ((size_t)(b * NN + n)) << 10;
        ushort4 u00 = r4[(base + iy0 * 32 + ix0) * 80 + v];
        ushort4 u01 = r4[(base + iy0 * 32 + ix1) * 80 + v];
        ushort4 u10 = r4[(base + iy1 * 32 + ix0) * 80 + v];
        ushort4 u11 = r4[(base + iy1 * 32 + ix1) * 80 + v];
        acc.x += w00 * bf2f(u00.x) + w01 * bf2f(u01.x) + w10 * bf2f(u10.x) + w11 * bf2f(u11.x);
        acc.y += w00 * bf2f(u00.y) + w01 * bf2f(u01.y) + w10 * bf2f(u10.y) + w11 * bf2f(u11.y);
        acc.z += w00 * bf2f(u00.z) + w01 * bf2f(u01.z) + w10 * bf2f(u10.z) + w11 * bf2f(u11.z);
        acc.w += w00 * bf2f(u00.w) + w01 * bf2f(u01.w) + w10 * bf2f(u10.w) + w11 * bf2f(u11.w);
    }
    nfloat4 nv = { acc.x, acc.y, acc.z, acc.w };
    __builtin_nontemporal_store(nv, ((nfloat4*)out) + (size_t)idx * 80 + v);
}

extern "C" void kernel_launch(void* const* d_in, const int* in_sizes, int n_in,
                              void* d_out, int out_size, void* d_ws, size_t ws_size,
                              hipStream_t stream) {
    const float* nhs   = (const float*)d_in[0];
    const float* attn  = (const float*)d_in[1];
    const float* boxes = (const float*)d_in[2];
    const int*   masks = (const int*)d_in[3];
    const int*   perm  = (const int*)d_in[4];
    const float* wred  = (const float*)d_in[5];
    const float* w1    = (const float*)d_in[6];
    const float* b1    = (const float*)d_in[7];
    const float* w2    = (const float*)d_in[8];
    const float* b2    = (const float*)d_in[9];
    float* out = (float*)d_out;
    float* ws = (float*)d_ws;
    unsigned short* roif = (unsigned short*)((char*)d_ws + (size_t)WS_FLOATS * 4);

    k_stage1<<<GRID_ROIF + GRID_RED, 320, 0, stream>>>(nhs, attn, boxes, masks, wred, ws, roif);
    k_fw<<<NB * NM, 256, 0, stream>>>(boxes, masks, ws);
    k_final<<<NB * HW / 4, 320, 0, stream>>>(attn, boxes, perm, w1, b1, w2, b2, ws, roif, out);
}

// Round 6
// 119.686 us; speedup vs baseline: 1.4662x; 1.0994x over previous
//
#include <hip/hip_runtime.h>
#include <hip/hip_bf16.h>

#define NB 2
#define NN 30
#define NC 320
#define NM 31
#define HW 4096
#define FMIN_F (-3.40282346638528859812e+38f)

typedef float nfloat4 __attribute__((ext_vector_type(4)));

// workspace layout (float offsets)
#define OFF_FSUM   0         // [2*4096]  sum_c nhs
#define OFF_FWRED  8192      // [2*4096]  sum_c nhs*w_reduce
#define OFF_ASUM   16384     // [2*4096]  sum_c attn
#define OFF_AWRED  24576     // [2*4096]  sum_c attn*w_reduce
#define OFF_Z      32768     // [62*4096] fw with -FLT_MAX sentinel where fg=false
#define OFF_MP     286720    // [64] per-(b,m) max of raw fw
#define WS_FLOATS  286784
// roi_feats bf16 at byte WS_FLOATS*4 (=1147136, 16B aligned), 2*30*1024*320*2 B

#define GRID_ROIF (NB * NN * 128)      // 8 cells/block -> 7680
#define GRID_RED  1639                 // ceil(8192/5)

__device__ __forceinline__ void get_box(const float* boxes, int b, int n,
                                        float& x1, float& y1, float& bw, float& bh) {
    const float* p = boxes + (b * NN + n) * 4;
    float X1 = p[0] * 64.0f - 0.5f;
    float Y1 = p[1] * 64.0f - 0.5f;
    float X2 = p[2] * 64.0f - 0.5f;
    float Y2 = p[3] * 64.0f - 0.5f;
    x1 = X1; y1 = Y1;
    bw = (X2 - X1) / 32.0f;
    bh = (Y2 - Y1) / 32.0f;
}

__device__ __forceinline__ unsigned short f2bf(float f) {
    __hip_bfloat16 h = __float2bfloat16(f);
    return *reinterpret_cast<unsigned short*>(&h);
}
__device__ __forceinline__ unsigned pack2(float a, float b) {
    return (unsigned)f2bf(a) | ((unsigned)f2bf(b) << 16);
}
__device__ __forceinline__ float blo(unsigned u) { return __uint_as_float(u << 16); }
__device__ __forceinline__ float bhi(unsigned u) { return __uint_as_float(u & 0xffff0000u); }

// ---- part A: full-channel roi_feats (bf16) for masked-in instances ----
// block = 8 cells x 40 lanes; thread = 8 channels.
// NOTE: boxes are clipped to [0,1] so every ROI-align sample is in (-0.5,63.5)
// => always valid. The cell's 2x2 samples span <=0.4px, so their 16 bilinear
// corner taps merge into a 3x3 stencil (typically 4-6 nonzero weights),
// computed once per cell by one thread and broadcast via LDS.
__device__ void do_roifeat(int blk, const float* __restrict__ nhs,
                           const float* __restrict__ boxes,
                           const int* __restrict__ masks,
                           unsigned* __restrict__ roif) {
    int bn = blk >> 7;                 // 8 cells/block, 128 blocks per (b,n)
    int n = bn % NN;
    int b = bn / NN;
    if (masks[b * NN + n] == 0) return;
    __shared__ float wsm[8][9];
    __shared__ int bsm[8];
    int tid = threadIdx.x;
    float x1, y1, bw, bh;
    get_box(boxes, b, n, x1, y1, bw, bh);

    if (tid < 8) {
        int cell = blk * 8 + tid;
        int q = cell & 31;
        int p = (cell >> 5) & 31;
        float W[9] = {0.f,0.f,0.f,0.f,0.f,0.f,0.f,0.f,0.f};
        float wys[4], wxs[4];
        int iy0s[4], ix0s[4];
        int iymin = 64, ixmin = 64;
#pragma unroll
        for (int s_ = 0; s_ < 4; s_++) {
            int di = s_ >> 1, dj = s_ & 1;
            float y = y1 + ((float)p + 0.25f + 0.5f * (float)di) * bh;
            float x = x1 + ((float)q + 0.25f + 0.5f * (float)dj) * bw;
            float yc = fminf(fmaxf(y, 0.0f), 63.0f);
            float xc = fminf(fmaxf(x, 0.0f), 63.0f);
            int iy0 = (int)floorf(yc), ix0 = (int)floorf(xc);
            wys[s_] = yc - (float)iy0;
            wxs[s_] = xc - (float)ix0;
            iy0s[s_] = iy0; ix0s[s_] = ix0;
            iymin = min(iymin, iy0); ixmin = min(ixmin, ix0);
        }
#pragma unroll
        for (int s_ = 0; s_ < 4; s_++) {
            float wy = wys[s_], wx = wxs[s_];
            int dy = iy0s[s_] - iymin;       // 0 or 1
            int dx = ix0s[s_] - ixmin;
            bool yt = (iy0s[s_] == 63);      // y1 clamped onto y0
            bool xt = (ix0s[s_] == 63);
            float ay0 = yt ? 1.0f : (1.0f - wy);
            float ay1 = yt ? 0.0f : wy;
            float ax0 = xt ? 1.0f : (1.0f - wx);
            float ax1 = xt ? 0.0f : wx;
            float r0 = dy ? 0.0f : ay0;
            float r1 = dy ? ay0  : ay1;
            float r2 = dy ? ay1  : 0.0f;
            float c0 = dx ? 0.0f : ax0;
            float c1 = dx ? ax0  : ax1;
            float c2 = dx ? ax1  : 0.0f;
            W[0] += r0 * c0; W[1] += r0 * c1; W[2] += r0 * c2;
            W[3] += r1 * c0; W[4] += r1 * c1; W[5] += r1 * c2;
            W[6] += r2 * c0; W[7] += r2 * c1; W[8] += r2 * c2;
        }
#pragma unroll
        for (int k = 0; k < 9; k++) wsm[tid][k] = W[k] * 0.25f;
        bsm[tid] = iymin * 64 + ixmin;
    }
    __syncthreads();

    int cid = tid / 40;
    int v = tid - cid * 40;           // 8-channel group index, [0,40)
    int cell = blk * 8 + cid;
    const float4* fb4 = (const float4*)(nhs + (size_t)b * HW * NC);
    int base = bsm[cid];
    float4 acc0 = make_float4(0.f, 0.f, 0.f, 0.f);
    float4 acc1 = make_float4(0.f, 0.f, 0.f, 0.f);
#pragma unroll
    for (int i = 0; i < 3; i++) {
#pragma unroll
        for (int j = 0; j < 3; j++) {
            float w = wsm[cid][i * 3 + j];
            if (w != 0.0f) {
                int off = (base + i * 64 + j) * 80 + v * 2;
                float4 f0 = fb4[off];
                float4 f1 = fb4[off + 1];
                acc0.x += w * f0.x; acc0.y += w * f0.y;
                acc0.z += w * f0.z; acc0.w += w * f0.w;
                acc1.x += w * f1.x; acc1.y += w * f1.y;
                acc1.z += w * f1.z; acc1.w += w * f1.w;
            }
        }
    }
    uint4 pk;
    pk.x = pack2(acc0.x, acc0.y);
    pk.y = pack2(acc0.z, acc0.w);
    pk.z = pack2(acc1.x, acc1.y);
    pk.w = pack2(acc1.z, acc1.w);
    ((uint4*)roif)[(size_t)cell * 40 + v] = pk;
}

// ---- part B: per-pixel channel reductions (one wave per row, float4) ----
__device__ void do_reduce(int rblk, const float* __restrict__ nhs,
                          const float* __restrict__ attn,
                          const float* __restrict__ wred, float* __restrict__ ws) {
    int wave = threadIdx.x >> 6;       // 0..4 (320 threads)
    int lane = threadIdx.x & 63;
    int row = rblk * 5 + wave;
    if (row >= NB * HW) return;
    const float4* n4 = (const float4*)(nhs + (size_t)row * NC);
    const float4* a4 = (const float4*)(attn + (size_t)row * NC);
    const float4* w4 = (const float4*)wred;
    float4 wv = w4[lane];
    float4 nv = n4[lane];
    float4 av = a4[lane];
    float s_n = nv.x + nv.y + nv.z + nv.w;
    float w_n = nv.x * wv.x + nv.y * wv.y + nv.z * wv.z + nv.w * wv.w;
    float s_a = av.x + av.y + av.z + av.w;
    float w_a = av.x * wv.x + av.y * wv.y + av.z * wv.z + av.w * wv.w;
    if (lane < 16) {                   // second chunk: float4 index 64..79
        float4 wv2 = w4[lane + 64];
        float4 nv2 = n4[lane + 64];
        float4 av2 = a4[lane + 64];
        s_n += nv2.x + nv2.y + nv2.z + nv2.w;
        w_n += nv2.x * wv2.x + nv2.y * wv2.y + nv2.z * wv2.z + nv2.w * wv2.w;
        s_a += av2.x + av2.y + av2.z + av2.w;
        w_a += av2.x * wv2.x + av2.y * wv2.y + av2.z * wv2.z + av2.w * wv2.w;
    }
#pragma unroll
    for (int off = 32; off > 0; off >>= 1) {
        s_n += __shfl_down(s_n, off, 64);
        w_n += __shfl_down(w_n, off, 64);
        s_a += __shfl_down(s_a, off, 64);
        w_a += __shfl_down(w_a, off, 64);
    }
    if (lane == 0) {
        ws[OFF_FSUM + row]  = s_n;
        ws[OFF_FWRED + row] = w_n;
        ws[OFF_ASUM + row]  = s_a;
        ws[OFF_AWRED + row] = w_a;
    }
}

// Kernel 1: roifeat (blocks [0,7680)) || reduce (blocks [7680,7680+1639))
__global__ void k_stage1(const float* __restrict__ nhs, const float* __restrict__ attn,
                         const float* __restrict__ boxes, const int* __restrict__ masks,
                         const float* __restrict__ wred, float* __restrict__ ws,
                         unsigned* __restrict__ roif) {
    int blk = blockIdx.x;
    if (blk < GRID_ROIF) {
        do_roifeat(blk, nhs, boxes, masks, roif);
    } else {
        do_reduce(blk - GRID_ROIF, nhs, attn, wred, ws);
    }
}

// Kernel 2 (fused roi_sums + fw): per (b,m) block, ROI-align the channel-reduced
// maps into LDS (m>=1), then unpool to all 4096 pixels -> Z (+sentinel) + max.
__global__ void k_fw(const float* __restrict__ boxes, const int* __restrict__ masks,
                     float* __restrict__ ws) {
    int bm = blockIdx.x;          // 0..61
    int b = bm / NM, m = bm % NM;
    __shared__ float rs[1024], rw[1024];
    __shared__ float red[256];
    float locmax = -INFINITY;
    int tid = threadIdx.x;
    if (m == 0) {
        for (int pix = tid; pix < HW; pix += 256) {
            float fwv = ws[OFF_AWRED + b * HW + pix];
            bool fg = (ws[OFF_ASUM + b * HW + pix] != 0.0f);
            ws[OFF_Z + (size_t)bm * HW + pix] = fg ? fwv : FMIN_F;
            locmax = fmaxf(locmax, fwv);
        }
    } else {
        int n = m - 1;
        int msk = masks[b * NN + n];
        if (msk) {
            float x1, y1, bw, bh;
            get_box(boxes, b, n, x1, y1, bw, bh);
            const float* fsum  = ws + OFF_FSUM + b * HW;
            const float* fwred = ws + OFF_FWRED + b * HW;
            for (int cell = tid; cell < 1024; cell += 256) {
                int q = cell & 31, p = cell >> 5;
                float accs = 0.f, accw = 0.f;
                // align samples always in-bounds (boxes clipped to [0,1])
#pragma unroll
                for (int di = 0; di < 2; di++) {
#pragma unroll
                    for (int dj = 0; dj < 2; dj++) {
                        float y = y1 + ((float)p + 0.25f + 0.5f * (float)di) * bh;
                        float x = x1 + ((float)q + 0.25f + 0.5f * (float)dj) * bw;
                        float yc = fminf(fmaxf(y, 0.0f), 63.0f);
                        float xc = fminf(fmaxf(x, 0.0f), 63.0f);
                        int iy0 = (int)floorf(yc), ix0 = (int)floorf(xc);
                        int iy1 = min(iy0 + 1, 63), ix1 = min(ix0 + 1, 63);
                        float wy = yc - (float)iy0, wx = xc - (float)ix0;
                        float w00 = (1.f - wy) * (1.f - wx), w01 = (1.f - wy) * wx;
                        float w10 = wy * (1.f - wx), w11 = wy * wx;
                        accs += w00 * fsum[iy0 * 64 + ix0] + w01 * fsum[iy0 * 64 + ix1]
                              + w10 * fsum[iy1 * 64 + ix0] + w11 * fsum[iy1 * 64 + ix1];
                        accw += w00 * fwred[iy0 * 64 + ix0] + w01 * fwred[iy0 * 64 + ix1]
                              + w10 * fwred[iy1 * 64 + ix0] + w11 * fwred[iy1 * 64 + ix1];
                    }
                }
                rs[cell] = accs * 0.25f;
                rw[cell] = accw * 0.25f;
            }
            __syncthreads();
            for (int pix = tid; pix < HW; pix += 256) {
                int h = pix >> 6, wp = pix & 63;
                float fwv = 0.0f;
                bool fg = false;
                float ry = ((float)h - y1) / bh - 0.5f;
                float rx = ((float)wp - x1) / bw - 0.5f;
                bool valid = (ry > -1.0f) && (ry < 32.0f) && (rx > -1.0f) && (rx < 32.0f);
                if (valid) {
                    float yc = fminf(fmaxf(ry, 0.0f), 31.0f);
                    float xc = fminf(fmaxf(rx, 0.0f), 31.0f);
                    int iy0 = (int)floorf(yc), ix0 = (int)floorf(xc);
                    int iy1 = min(iy0 + 1, 31), ix1 = min(ix0 + 1, 31);
                    float wy = yc - (float)iy0, wx = xc - (float)ix0;
                    float w00 = (1.f - wy) * (1.f - wx), w01 = (1.f - wy) * wx;
                    float w10 = wy * (1.f - wx), w11 = wy * wx;
                    fwv = w00 * rw[iy0 * 32 + ix0] + w01 * rw[iy0 * 32 + ix1]
                        + w10 * rw[iy1 * 32 + ix0] + w11 * rw[iy1 * 32 + ix1];
                    float su = w00 * rs[iy0 * 32 + ix0] + w01 * rs[iy0 * 32 + ix1]
                             + w10 * rs[iy1 * 32 + ix0] + w11 * rs[iy1 * 32 + ix1];
                    fg = (su != 0.0f);
                }
                ws[OFF_Z + (size_t)bm * HW + pix] = fg ? fwv : FMIN_F;
                locmax = fmaxf(locmax, fwv);
            }
        } else {
            // masked-out: fw == 0 everywhere, fg false
            for (int pix = tid; pix < HW; pix += 256)
                ws[OFF_Z + (size_t)bm * HW + pix] = FMIN_F;
            locmax = 0.0f;
        }
    }
    red[tid] = locmax;
    __syncthreads();
    for (int s = 128; s > 0; s >>= 1) {
        if (tid < s) red[tid] = fmaxf(red[tid], red[tid + s]);
        __syncthreads();
    }
    if (tid == 0) ws[OFF_MP + bm] = red[0];
}

// Kernel 3: fused MLP + per-pixel softmax + final gather.
// block = 8 pixels x 40 lanes; thread = 8 channels.
__global__ void k_final(const float* __restrict__ attn, const float* __restrict__ boxes,
                        const int* __restrict__ perm, const float* __restrict__ w1,
                        const float* __restrict__ b1, const float* __restrict__ w2,
                        const float* __restrict__ b2, const float* __restrict__ ws,
                        const unsigned* __restrict__ roif, float* __restrict__ out) {
    __shared__ float mpg[NM], hb[NM], scal[32], wbuf[8][32];
    int t = threadIdx.x;
    int idx0 = blockIdx.x * 8;         // all 8 pixels share the same b
    int b = idx0 >> 12;

    // stage 1: tiny MLP (redundant per block)
    if (t < NM) {
        mpg[t] = (t == 0) ? ws[OFF_MP + b * NM]
                          : ws[OFF_MP + b * NM + 1 + perm[t - 1]];
    }
    __syncthreads();
    if (t < NM) {
        float a = b1[t];
#pragma unroll
        for (int k = 0; k < NM; k++) a += mpg[k] * w1[k * NM + t];
        hb[t] = fmaxf(a, 0.0f);
    }
    __syncthreads();
    if (t < NM) {
        float a = b2[t];
#pragma unroll
        for (int k = 0; k < NM; k++) a += hb[k] * w2[k * NM + t];
        float sig = 1.0f / (1.0f + expf(-a));
        if (t == 0) scal[0] = sig;
        else        scal[1 + perm[t - 1]] = sig;
    }
    __syncthreads();

    // stage 2: softmax for the 8 pixels (threads 0..255; 32 lanes per pixel)
    if (t < 256) {
        int pg = t >> 5, m = t & 31;
        int pix = (idx0 + pg) & 4095;
        float zz = FMIN_F;
        if (m < NM) {
            float v = ws[OFF_Z + (size_t)(b * NM + m) * HW + pix];
            zz = (v == FMIN_F) ? FMIN_F : v * scal[m];
        }
        float mx = zz;
#pragma unroll
        for (int off = 16; off > 0; off >>= 1)
            mx = fmaxf(mx, __shfl_xor(mx, off, 64));
        float e = (m < NM) ? expf(zz - mx) : 0.0f;
        float s = e;
#pragma unroll
        for (int off = 16; off > 0; off >>= 1)
            s += __shfl_xor(s, off, 64);
        if (m < NM) wbuf[pg][m] = e / s;
    }
    __syncthreads();

    // stage 3: gather
    int pid = t / 40;
    int v = t - pid * 40;              // 8-channel group, [0,40)
    int idx = idx0 + pid;
    int pix = idx & 4095;
    int h = pix >> 6, wp = pix & 63;
    float w0 = wbuf[pid][0];
    const float4* at4 = (const float4*)attn;
    float4 a0 = at4[(size_t)idx * 80 + v * 2];
    float4 a1 = at4[(size_t)idx * 80 + v * 2 + 1];
    float4 acc0, acc1;
    acc0.x = a0.x * w0; acc0.y = a0.y * w0; acc0.z = a0.z * w0; acc0.w = a0.w * w0;
    acc1.x = a1.x * w0; acc1.y = a1.y * w0; acc1.z = a1.z * w0; acc1.w = a1.w * w0;
    const uint4* r4 = (const uint4*)roif;
    for (int n = 0; n < NN; n++) {
        float wn = wbuf[pid][n + 1];
        if (wn == 0.0f) continue;      // uniform across the 40-lane group
        float x1, y1, bw, bh;
        get_box(boxes, b, n, x1, y1, bw, bh);
        float ry = ((float)h - y1) / bh - 0.5f;
        float rx = ((float)wp - x1) / bw - 0.5f;
        float yc = fminf(fmaxf(ry, 0.0f), 31.0f);
        float xc = fminf(fmaxf(rx, 0.0f), 31.0f);
        int iy0 = (int)floorf(yc), ix0 = (int)floorf(xc);
        int iy1 = min(iy0 + 1, 31), ix1 = min(ix0 + 1, 31);
        float wy = yc - (float)iy0, wx = xc - (float)ix0;
        float w00 = (1.f - wy) * (1.f - wx) * wn, w01 = (1.f - wy) * wx * wn;
        float w10 = wy * (1.f - wx) * wn, w11 = wy * wx * wn;
        size_t base = ((size_t)(b * NN + n)) << 10;
        uint4 U00 = r4[(base + iy0 * 32 + ix0) * 40 + v];
        uint4 U01 = r4[(base + iy0 * 32 + ix1) * 40 + v];
        uint4 U10 = r4[(base + iy1 * 32 + ix0) * 40 + v];
        uint4 U11 = r4[(base + iy1 * 32 + ix1) * 40 + v];
        acc0.x += w00 * blo(U00.x) + w01 * blo(U01.x) + w10 * blo(U10.x) + w11 * blo(U11.x);
        acc0.y += w00 * bhi(U00.x) + w01 * bhi(U01.x) + w10 * bhi(U10.x) + w11 * bhi(U11.x);
        acc0.z += w00 * blo(U00.y) + w01 * blo(U01.y) + w10 * blo(U10.y) + w11 * blo(U11.y);
        acc0.w += w00 * bhi(U00.y) + w01 * bhi(U01.y) + w10 * bhi(U10.y) + w11 * bhi(U11.y);
        acc1.x += w00 * blo(U00.z) + w01 * blo(U01.z) + w10 * blo(U10.z) + w11 * blo(U11.z);
        acc1.y += w00 * bhi(U00.z) + w01 * bhi(U01.z) + w10 * bhi(U10.z) + w11 * bhi(U11.z);
        acc1.z += w00 * blo(U00.w) + w01 * blo(U01.w) + w10 * blo(U10.w) + w11 * blo(U11.w);
        acc1.w += w00 * bhi(U00.w) + w01 * bhi(U01.w) + w10 * bhi(U10.w) + w11 * bhi(U11.w);
    }
    nfloat4 nv0 = { acc0.x, acc0.y, acc0.z, acc0.w };
    nfloat4 nv1 = { acc1.x, acc1.y, acc1.z, acc1.w };
    __builtin_nontemporal_store(nv0, ((nfloat4*)out) + (size_t)idx * 80 + v * 2);
    __builtin_nontemporal_store(nv1, ((nfloat4*)out) + (size_t)idx * 80 + v * 2 + 1);
}

extern "C" void kernel_launch(void* const* d_in, const int* in_sizes, int n_in,
                              void* d_out, int out_size, void* d_ws, size_t ws_size,
                              hipStream_t stream) {
    const float* nhs   = (const float*)d_in[0];
    const float* attn  = (const float*)d_in[1];
    const float* boxes = (const float*)d_in[2];
    const int*   masks = (const int*)d_in[3];
    const int*   perm  = (const int*)d_in[4];
    const float* wred  = (const float*)d_in[5];
    const float* w1    = (const float*)d_in[6];
    const float* b1    = (const float*)d_in[7];
    const float* w2    = (const float*)d_in[8];
    const float* b2    = (const float*)d_in[9];
    float* out = (float*)d_out;
    float* ws = (float*)d_ws;
    unsigned* roif = (unsigned*)((char*)d_ws + (size_t)WS_FLOATS * 4);

    k_stage1<<<GRID_ROIF + GRID_RED, 320, 0, stream>>>(nhs, attn, boxes, masks, wred, ws, roif);
    k_fw<<<NB * NM, 256, 0, stream>>>(boxes, masks, ws);
    k_final<<<NB * HW / 8, 320, 0, stream>>>(attn, boxes, perm, w1, b1, w2, b2, ws, roif, out);
}

// Round 7
// 117.431 us; speedup vs baseline: 1.4944x; 1.0192x over previous
//
#include <hip/hip_runtime.h>
#include <hip/hip_bf16.h>

#define NB 2
#define NN 30
#define NC 320
#define NM 31
#define HW 4096
#define FMIN_F (-3.40282346638528859812e+38f)
#define PCH 8                  // pixel chunks per (b,m) in k_fw

typedef float nfloat4 __attribute__((ext_vector_type(4)));

// workspace layout (float offsets)
#define OFF_FSUM   0         // [2*4096]  sum_c nhs
#define OFF_FWRED  8192      // [2*4096]  sum_c nhs*w_reduce
#define OFF_ASUM   16384     // [2*4096]  sum_c attn
#define OFF_AWRED  24576     // [2*4096]  sum_c attn*w_reduce
#define OFF_Z      32768     // [62*4096] fw with -FLT_MAX sentinel where fg=false
#define OFF_MP     286720    // [64] per-(b,m) max of raw fw (monotone-uint encoded)
#define WS_FLOATS  286784
// roi_feats bf16 at byte WS_FLOATS*4 (=1147136, 16B aligned), 2*30*1024*320*2 B

#define GRID_ROIF (NB * NN * 128)      // 8 cells/block -> 7680
#define GRID_RED  1639                 // ceil(8192/5)

__device__ __forceinline__ void get_box(const float* boxes, int b, int n,
                                        float& x1, float& y1, float& bw, float& bh) {
    const float* p = boxes + (b * NN + n) * 4;
    float X1 = p[0] * 64.0f - 0.5f;
    float Y1 = p[1] * 64.0f - 0.5f;
    float X2 = p[2] * 64.0f - 0.5f;
    float Y2 = p[3] * 64.0f - 0.5f;
    x1 = X1; y1 = Y1;
    bw = (X2 - X1) / 32.0f;
    bh = (Y2 - Y1) / 32.0f;
}

__device__ __forceinline__ unsigned short f2bf(float f) {
    __hip_bfloat16 h = __float2bfloat16(f);
    return *reinterpret_cast<unsigned short*>(&h);
}
__device__ __forceinline__ unsigned pack2(float a, float b) {
    return (unsigned)f2bf(a) | ((unsigned)f2bf(b) << 16);
}
__device__ __forceinline__ float blo(unsigned u) { return __uint_as_float(u << 16); }
__device__ __forceinline__ float bhi(unsigned u) { return __uint_as_float(u & 0xffff0000u); }

// monotone float <-> uint encoding for atomicMax over signed floats
__device__ __forceinline__ unsigned encf(float f) {
    unsigned u = __float_as_uint(f);
    return (u & 0x80000000u) ? ~u : (u | 0x80000000u);
}
__device__ __forceinline__ float decf(unsigned e) {
    unsigned u = (e & 0x80000000u) ? (e & 0x7fffffffu) : ~e;
    return __uint_as_float(u);
}

// ---- part A: full-channel roi_feats (bf16) for masked-in instances ----
// block = 8 cells x 40 lanes; thread = 8 channels. Boxes clipped to [0,1] so
// align samples are always in-bounds; the 2x2 samples' 16 taps merge into a
// 3x3 stencil computed once per cell and broadcast via LDS.
__device__ void do_roifeat(int blk, const float* __restrict__ nhs,
                           const float* __restrict__ boxes,
                           const int* __restrict__ masks,
                           unsigned* __restrict__ roif) {
    int bn = blk >> 7;                 // 8 cells/block, 128 blocks per (b,n)
    int n = bn % NN;
    int b = bn / NN;
    if (masks[b * NN + n] == 0) return;
    __shared__ float wsm[8][9];
    __shared__ int bsm[8];
    int tid = threadIdx.x;
    float x1, y1, bw, bh;
    get_box(boxes, b, n, x1, y1, bw, bh);

    if (tid < 8) {
        int cell = blk * 8 + tid;
        int q = cell & 31;
        int p = (cell >> 5) & 31;
        float W[9] = {0.f,0.f,0.f,0.f,0.f,0.f,0.f,0.f,0.f};
        float wys[4], wxs[4];
        int iy0s[4], ix0s[4];
        int iymin = 64, ixmin = 64;
#pragma unroll
        for (int s_ = 0; s_ < 4; s_++) {
            int di = s_ >> 1, dj = s_ & 1;
            float y = y1 + ((float)p + 0.25f + 0.5f * (float)di) * bh;
            float x = x1 + ((float)q + 0.25f + 0.5f * (float)dj) * bw;
            float yc = fminf(fmaxf(y, 0.0f), 63.0f);
            float xc = fminf(fmaxf(x, 0.0f), 63.0f);
            int iy0 = (int)floorf(yc), ix0 = (int)floorf(xc);
            wys[s_] = yc - (float)iy0;
            wxs[s_] = xc - (float)ix0;
            iy0s[s_] = iy0; ix0s[s_] = ix0;
            iymin = min(iymin, iy0); ixmin = min(ixmin, ix0);
        }
#pragma unroll
        for (int s_ = 0; s_ < 4; s_++) {
            float wy = wys[s_], wx = wxs[s_];
            int dy = iy0s[s_] - iymin;
            int dx = ix0s[s_] - ixmin;
            bool yt = (iy0s[s_] == 63);
            bool xt = (ix0s[s_] == 63);
            float ay0 = yt ? 1.0f : (1.0f - wy);
            float ay1 = yt ? 0.0f : wy;
            float ax0 = xt ? 1.0f : (1.0f - wx);
            float ax1 = xt ? 0.0f : wx;
            float r0 = dy ? 0.0f : ay0;
            float r1 = dy ? ay0  : ay1;
            float r2 = dy ? ay1  : 0.0f;
            float c0 = dx ? 0.0f : ax0;
            float c1 = dx ? ax0  : ax1;
            float c2 = dx ? ax1  : 0.0f;
            W[0] += r0 * c0; W[1] += r0 * c1; W[2] += r0 * c2;
            W[3] += r1 * c0; W[4] += r1 * c1; W[5] += r1 * c2;
            W[6] += r2 * c0; W[7] += r2 * c1; W[8] += r2 * c2;
        }
#pragma unroll
        for (int k = 0; k < 9; k++) wsm[tid][k] = W[k] * 0.25f;
        bsm[tid] = iymin * 64 + ixmin;
    }
    __syncthreads();

    int cid = tid / 40;
    int v = tid - cid * 40;
    int cell = blk * 8 + cid;
    const float4* fb4 = (const float4*)(nhs + (size_t)b * HW * NC);
    int base = bsm[cid];
    float4 acc0 = make_float4(0.f, 0.f, 0.f, 0.f);
    float4 acc1 = make_float4(0.f, 0.f, 0.f, 0.f);
#pragma unroll
    for (int i = 0; i < 3; i++) {
#pragma unroll
        for (int j = 0; j < 3; j++) {
            float w = wsm[cid][i * 3 + j];
            if (w != 0.0f) {
                int off = (base + i * 64 + j) * 80 + v * 2;
                float4 f0 = fb4[off];
                float4 f1 = fb4[off + 1];
                acc0.x += w * f0.x; acc0.y += w * f0.y;
                acc0.z += w * f0.z; acc0.w += w * f0.w;
                acc1.x += w * f1.x; acc1.y += w * f1.y;
                acc1.z += w * f1.z; acc1.w += w * f1.w;
            }
        }
    }
    uint4 pk;
    pk.x = pack2(acc0.x, acc0.y);
    pk.y = pack2(acc0.z, acc0.w);
    pk.z = pack2(acc1.x, acc1.y);
    pk.w = pack2(acc1.z, acc1.w);
    ((uint4*)roif)[(size_t)cell * 40 + v] = pk;
}

// ---- part B: per-pixel channel reductions (one wave per row, float4) ----
__device__ void do_reduce(int rblk, const float* __restrict__ nhs,
                          const float* __restrict__ attn,
                          const float* __restrict__ wred, float* __restrict__ ws) {
    // first reduce block also zero-inits the encoded MP slots (k_fw atomicMax's later)
    if (rblk == 0 && threadIdx.x < 64)
        ((unsigned*)(ws + OFF_MP))[threadIdx.x] = 0u;
    int wave = threadIdx.x >> 6;
    int lane = threadIdx.x & 63;
    int row = rblk * 5 + wave;
    if (row >= NB * HW) return;
    const float4* n4 = (const float4*)(nhs + (size_t)row * NC);
    const float4* a4 = (const float4*)(attn + (size_t)row * NC);
    const float4* w4 = (const float4*)wred;
    float4 wv = w4[lane];
    float4 nv = n4[lane];
    float4 av = a4[lane];
    float s_n = nv.x + nv.y + nv.z + nv.w;
    float w_n = nv.x * wv.x + nv.y * wv.y + nv.z * wv.z + nv.w * wv.w;
    float s_a = av.x + av.y + av.z + av.w;
    float w_a = av.x * wv.x + av.y * wv.y + av.z * wv.z + av.w * wv.w;
    if (lane < 16) {
        float4 wv2 = w4[lane + 64];
        float4 nv2 = n4[lane + 64];
        float4 av2 = a4[lane + 64];
        s_n += nv2.x + nv2.y + nv2.z + nv2.w;
        w_n += nv2.x * wv2.x + nv2.y * wv2.y + nv2.z * wv2.z + nv2.w * wv2.w;
        s_a += av2.x + av2.y + av2.z + av2.w;
        w_a += av2.x * wv2.x + av2.y * wv2.y + av2.z * wv2.z + av2.w * wv2.w;
    }
#pragma unroll
    for (int off = 32; off > 0; off >>= 1) {
        s_n += __shfl_down(s_n, off, 64);
        w_n += __shfl_down(w_n, off, 64);
        s_a += __shfl_down(s_a, off, 64);
        w_a += __shfl_down(w_a, off, 64);
    }
    if (lane == 0) {
        ws[OFF_FSUM + row]  = s_n;
        ws[OFF_FWRED + row] = w_n;
        ws[OFF_ASUM + row]  = s_a;
        ws[OFF_AWRED + row] = w_a;
    }
}

// Kernel 1: roifeat (blocks [0,7680)) || reduce (blocks [7680,7680+1639))
__global__ void k_stage1(const float* __restrict__ nhs, const float* __restrict__ attn,
                         const float* __restrict__ boxes, const int* __restrict__ masks,
                         const float* __restrict__ wred, float* __restrict__ ws,
                         unsigned* __restrict__ roif) {
    int blk = blockIdx.x;
    if (blk < GRID_ROIF) {
        do_roifeat(blk, nhs, boxes, masks, roif);
    } else {
        do_reduce(blk - GRID_ROIF, nhs, attn, wred, ws);
    }
}

// Kernel 2 (fused roi_sums + fw), chunked: block = ((b,m), chunk of 512 pixels).
// For m>=1 masked-in: build only the needed rows of the 32x32 reduced-ROI grid
// in LDS, then unpool the chunk's 512 pixels -> Z (+sentinel); per-bm max via
// atomicMax on encoded floats.
__global__ void k_fw(const float* __restrict__ boxes, const int* __restrict__ masks,
                     float* __restrict__ ws) {
    int bm = blockIdx.x / PCH;     // 0..61
    int ch = blockIdx.x % PCH;     // 0..7 -> pixels [ch*512, (ch+1)*512)
    int b = bm / NM, m = bm % NM;
    int pix0 = ch * (HW / PCH);
    __shared__ float rs[1024], rw[1024];
    __shared__ float red[256];
    float locmax = -INFINITY;
    int tid = threadIdx.x;
    if (m == 0) {
        for (int pix = pix0 + tid; pix < pix0 + HW / PCH; pix += 256) {
            float fwv = ws[OFF_AWRED + b * HW + pix];
            bool fg = (ws[OFF_ASUM + b * HW + pix] != 0.0f);
            ws[OFF_Z + (size_t)bm * HW + pix] = fg ? fwv : FMIN_F;
            locmax = fmaxf(locmax, fwv);
        }
    } else {
        int n = m - 1;
        int msk = masks[b * NN + n];
        if (msk) {
            float x1, y1, bw, bh;
            get_box(boxes, b, n, x1, y1, bw, bh);
            // ROI rows touched by this chunk's 8 image rows (conservative +/-1)
            int h0 = pix0 >> 6;
            float ry_lo = ((float)h0 - y1) / bh - 0.5f;
            float ry_hi = ((float)(h0 + 7) - y1) / bh - 0.5f;
            int iy_lo = max(0, (int)floorf(fminf(fmaxf(ry_lo, 0.0f), 31.0f)) - 1);
            int iy_hi = min(31, (int)floorf(fminf(fmaxf(ry_hi, 0.0f), 31.0f)) + 2);
            const float* fsum  = ws + OFF_FSUM + b * HW;
            const float* fwred = ws + OFF_FWRED + b * HW;
            for (int cell = tid; cell < 1024; cell += 256) {
                int q = cell & 31, p = cell >> 5;
                if (p < iy_lo || p > iy_hi) continue;
                float accs = 0.f, accw = 0.f;
#pragma unroll
                for (int di = 0; di < 2; di++) {
#pragma unroll
                    for (int dj = 0; dj < 2; dj++) {
                        float y = y1 + ((float)p + 0.25f + 0.5f * (float)di) * bh;
                        float x = x1 + ((float)q + 0.25f + 0.5f * (float)dj) * bw;
                        float yc = fminf(fmaxf(y, 0.0f), 63.0f);
                        float xc = fminf(fmaxf(x, 0.0f), 63.0f);
                        int iy0 = (int)floorf(yc), ix0 = (int)floorf(xc);
                        int iy1 = min(iy0 + 1, 63), ix1 = min(ix0 + 1, 63);
                        float wy = yc - (float)iy0, wx = xc - (float)ix0;
                        float w00 = (1.f - wy) * (1.f - wx), w01 = (1.f - wy) * wx;
                        float w10 = wy * (1.f - wx), w11 = wy * wx;
                        accs += w00 * fsum[iy0 * 64 + ix0] + w01 * fsum[iy0 * 64 + ix1]
                              + w10 * fsum[iy1 * 64 + ix0] + w11 * fsum[iy1 * 64 + ix1];
                        accw += w00 * fwred[iy0 * 64 + ix0] + w01 * fwred[iy0 * 64 + ix1]
                              + w10 * fwred[iy1 * 64 + ix0] + w11 * fwred[iy1 * 64 + ix1];
                    }
                }
                rs[cell] = accs * 0.25f;
                rw[cell] = accw * 0.25f;
            }
            __syncthreads();
            for (int pix = pix0 + tid; pix < pix0 + HW / PCH; pix += 256) {
                int h = pix >> 6, wp = pix & 63;
                float fwv = 0.0f;
                bool fg = false;
                float ry = ((float)h - y1) / bh - 0.5f;
                float rx = ((float)wp - x1) / bw - 0.5f;
                bool valid = (ry > -1.0f) && (ry < 32.0f) && (rx > -1.0f) && (rx < 32.0f);
                if (valid) {
                    float yc = fminf(fmaxf(ry, 0.0f), 31.0f);
                    float xc = fminf(fmaxf(rx, 0.0f), 31.0f);
                    int iy0 = (int)floorf(yc), ix0 = (int)floorf(xc);
                    int iy1 = min(iy0 + 1, 31), ix1 = min(ix0 + 1, 31);
                    float wy = yc - (float)iy0, wx = xc - (float)ix0;
                    float w00 = (1.f - wy) * (1.f - wx), w01 = (1.f - wy) * wx;
                    float w10 = wy * (1.f - wx), w11 = wy * wx;
                    fwv = w00 * rw[iy0 * 32 + ix0] + w01 * rw[iy0 * 32 + ix1]
                        + w10 * rw[iy1 * 32 + ix0] + w11 * rw[iy1 * 32 + ix1];
                    float su = w00 * rs[iy0 * 32 + ix0] + w01 * rs[iy0 * 32 + ix1]
                             + w10 * rs[iy1 * 32 + ix0] + w11 * rs[iy1 * 32 + ix1];
                    fg = (su != 0.0f);
                }
                ws[OFF_Z + (size_t)bm * HW + pix] = fg ? fwv : FMIN_F;
                locmax = fmaxf(locmax, fwv);
            }
        } else {
            for (int pix = pix0 + tid; pix < pix0 + HW / PCH; pix += 256)
                ws[OFF_Z + (size_t)bm * HW + pix] = FMIN_F;
            locmax = 0.0f;
        }
    }
    red[tid] = locmax;
    __syncthreads();
    for (int s = 128; s > 0; s >>= 1) {
        if (tid < s) red[tid] = fmaxf(red[tid], red[tid + s]);
        __syncthreads();
    }
    if (tid == 0)
        atomicMax((unsigned*)(ws + OFF_MP) + bm, encf(red[0]));
}

// Kernel 3: fused MLP + per-pixel softmax + final gather with compact
// active-ROI list. block = 8 pixels x 40 lanes; thread = 8 channels.
__global__ void k_final(const float* __restrict__ attn, const float* __restrict__ boxes,
                        const int* __restrict__ perm, const float* __restrict__ w1,
                        const float* __restrict__ b1, const float* __restrict__ w2,
                        const float* __restrict__ b2, const float* __restrict__ ws,
                        const unsigned* __restrict__ roif, float* __restrict__ out) {
    __shared__ float mpg[NM], hb[NM], scal[32], wbuf[8][32];
    __shared__ int acnt[8];
    __shared__ unsigned char alist[8][NN];
    int t = threadIdx.x;
    int idx0 = blockIdx.x * 8;         // all 8 pixels share the same b
    int b = idx0 >> 12;

    // stage 1: tiny MLP (redundant per block)
    if (t < 8) acnt[t] = 0;
    if (t < NM) {
        unsigned e = ((const unsigned*)(ws + OFF_MP))[b * NM + ((t == 0) ? 0 : 1 + perm[t - 1])];
        mpg[t] = decf(e);
    }
    __syncthreads();
    if (t < NM) {
        float a = b1[t];
#pragma unroll
        for (int k = 0; k < NM; k++) a += mpg[k] * w1[k * NM + t];
        hb[t] = fmaxf(a, 0.0f);
    }
    __syncthreads();
    if (t < NM) {
        float a = b2[t];
#pragma unroll
        for (int k = 0; k < NM; k++) a += hb[k] * w2[k * NM + t];
        float sig = 1.0f / (1.0f + expf(-a));
        if (t == 0) scal[0] = sig;
        else        scal[1 + perm[t - 1]] = sig;
    }
    __syncthreads();

    // stage 2: softmax for the 8 pixels (threads 0..255; 32 lanes per pixel)
    if (t < 256) {
        int pg = t >> 5, m = t & 31;
        int pix = (idx0 + pg) & 4095;
        float zz = FMIN_F;
        if (m < NM) {
            float v = ws[OFF_Z + (size_t)(b * NM + m) * HW + pix];
            zz = (v == FMIN_F) ? FMIN_F : v * scal[m];
        }
        float mx = zz;
#pragma unroll
        for (int off = 16; off > 0; off >>= 1)
            mx = fmaxf(mx, __shfl_xor(mx, off, 64));
        float e = (m < NM) ? expf(zz - mx) : 0.0f;
        float s = e;
#pragma unroll
        for (int off = 16; off > 0; off >>= 1)
            s += __shfl_xor(s, off, 64);
        if (m < NM) {
            float w = e / s;
            wbuf[pg][m] = w;
            if (m >= 1 && w != 0.0f) {
                int pos = atomicAdd(&acnt[pg], 1);
                alist[pg][pos] = (unsigned char)(m - 1);
            }
        }
    }
    __syncthreads();

    // stage 3: gather over compact active list
    int pid = t / 40;
    int v = t - pid * 40;
    int idx = idx0 + pid;
    int pix = idx & 4095;
    int h = pix >> 6, wp = pix & 63;
    float w0 = wbuf[pid][0];
    const float4* at4 = (const float4*)attn;
    float4 a0 = at4[(size_t)idx * 80 + v * 2];
    float4 a1 = at4[(size_t)idx * 80 + v * 2 + 1];
    float4 acc0, acc1;
    acc0.x = a0.x * w0; acc0.y = a0.y * w0; acc0.z = a0.z * w0; acc0.w = a0.w * w0;
    acc1.x = a1.x * w0; acc1.y = a1.y * w0; acc1.z = a1.z * w0; acc1.w = a1.w * w0;
    const uint4* r4 = (const uint4*)roif;
    int na = acnt[pid];
    for (int k = 0; k < na; k++) {
        int n = alist[pid][k];
        float wn = wbuf[pid][n + 1];
        float x1, y1, bw, bh;
        get_box(boxes, b, n, x1, y1, bw, bh);
        float ry = ((float)h - y1) / bh - 0.5f;
        float rx = ((float)wp - x1) / bw - 0.5f;
        float yc = fminf(fmaxf(ry, 0.0f), 31.0f);
        float xc = fminf(fmaxf(rx, 0.0f), 31.0f);
        int iy0 = (int)floorf(yc), ix0 = (int)floorf(xc);
        int iy1 = min(iy0 + 1, 31), ix1 = min(ix0 + 1, 31);
        float wy = yc - (float)iy0, wx = xc - (float)ix0;
        float w00 = (1.f - wy) * (1.f - wx) * wn, w01 = (1.f - wy) * wx * wn;
        float w10 = wy * (1.f - wx) * wn, w11 = wy * wx * wn;
        size_t base = ((size_t)(b * NN + n)) << 10;
        uint4 U00 = r4[(base + iy0 * 32 + ix0) * 40 + v];
        uint4 U01 = r4[(base + iy0 * 32 + ix1) * 40 + v];
        uint4 U10 = r4[(base + iy1 * 32 + ix0) * 40 + v];
        uint4 U11 = r4[(base + iy1 * 32 + ix1) * 40 + v];
        acc0.x += w00 * blo(U00.x) + w01 * blo(U01.x) + w10 * blo(U10.x) + w11 * blo(U11.x);
        acc0.y += w00 * bhi(U00.x) + w01 * bhi(U01.x) + w10 * bhi(U10.x) + w11 * bhi(U11.x);
        acc0.z += w00 * blo(U00.y) + w01 * blo(U01.y) + w10 * blo(U10.y) + w11 * blo(U11.y);
        acc0.w += w00 * bhi(U00.y) + w01 * bhi(U01.y) + w10 * bhi(U10.y) + w11 * bhi(U11.y);
        acc1.x += w00 * blo(U00.z) + w01 * blo(U01.z) + w10 * blo(U10.z) + w11 * blo(U11.z);
        acc1.y += w00 * bhi(U00.z) + w01 * bhi(U01.z) + w10 * bhi(U10.z) + w11 * bhi(U11.z);
        acc1.z += w00 * blo(U00.w) + w01 * blo(U01.w) + w10 * blo(U10.w) + w11 * blo(U11.w);
        acc1.w += w00 * bhi(U00.w) + w01 * bhi(U01.w) + w10 * bhi(U10.w) + w11 * bhi(U11.w);
    }
    nfloat4 nv0 = { acc0.x, acc0.y, acc0.z, acc0.w };
    nfloat4 nv1 = { acc1.x, acc1.y, acc1.z, acc1.w };
    __builtin_nontemporal_store(nv0, ((nfloat4*)out) + (size_t)idx * 80 + v * 2);
    __builtin_nontemporal_store(nv1, ((nfloat4*)out) + (size_t)idx * 80 + v * 2 + 1);
}

extern "C" void kernel_launch(void* const* d_in, const int* in_sizes, int n_in,
                              void* d_out, int out_size, void* d_ws, size_t ws_size,
                              hipStream_t stream) {
    const float* nhs   = (const float*)d_in[0];
    const float* attn  = (const float*)d_in[1];
    const float* boxes = (const float*)d_in[2];
    const int*   masks = (const int*)d_in[3];
    const int*   perm  = (const int*)d_in[4];
    const float* wred  = (const float*)d_in[5];
    const float* w1    = (const float*)d_in[6];
    const float* b1    = (const float*)d_in[7];
    const float* w2    = (const float*)d_in[8];
    const float* b2    = (const float*)d_in[9];
    float* out = (float*)d_out;
    float* ws = (float*)d_ws;
    unsigned* roif = (unsigned*)((char*)d_ws + (size_t)WS_FLOATS * 4);

    k_stage1<<<GRID_ROIF + GRID_RED, 320, 0, stream>>>(nhs, attn, boxes, masks, wred, ws, roif);
    k_fw<<<NB * NM * PCH, 256, 0, stream>>>(boxes, masks, ws);
    k_final<<<NB * HW / 8, 320, 0, stream>>>(attn, boxes, perm, w1, b1, w2, b2, ws, roif, out);
}